// Round 6
// baseline (4627.373 us; speedup 1.0000x reference)
//
#include <hip/hip_runtime.h>

#define M_TOTAL 65536   // B*T rows
#define DDIM    128     // latent dim (GEMM K)
#define KCODES  1024    // codebook size (GEMM N)
#define NQ      8       // RVQ stages
#define RROWS   64      // rows per block -> 1024 blocks (512 co-resident, 2 rounds)
#define SNC     32      // screen codes per chunk (register B-tiles)
#define SNCH    (KCODES / SNC)         // 32 screen chunks
#define TAU     0.15f   // margin threshold in REF dist units (validated; screen dist = ref/2)
#define FB      8       // fixup rows per batched codebook scan

typedef _Float16 half8 __attribute__((ext_vector_type(8)));
typedef float    f32x4 __attribute__((ext_vector_type(4)));

// XOR-swizzled [64][128] f32 FS tile: row r, 16B-block c4 at slot c4^(r&7).
// Fixup dot-reads (lane=row, same k4) become 8-lane broadcasts over all 32
// banks (conflict-free); staging writes are 2-way (free).
__device__ __forceinline__ float4* fsf4(float* FS, int r, int c4) {
  return (float4*)((char*)FS + r * 512 + (((c4) ^ (r & 7)) << 4));
}

// ---------------- ||e||^2 (verified round-1 semantics) ----------------
__global__ __launch_bounds__(256) void enorm_kernel(const float* __restrict__ embed,
                                                    float* __restrict__ enorm) {
  int c = blockIdx.x * 4 + (threadIdx.x >> 6);
  int lane = threadIdx.x & 63;
  const float* e = embed + (size_t)c * DDIM;
  float v0 = e[lane];
  float v1 = e[lane + 64];
  float s = fmaf(v0, v0, v1 * v1);
  #pragma unroll
  for (int off = 32; off > 0; off >>= 1) s += __shfl_down(s, off);
  if (lane == 0) enorm[c] = s;
}

// ---------------- embed -> f16 plane, plain row-major (B read direct from L2) ----
__global__ __launch_bounds__(256) void esplit16_kernel(const float* __restrict__ embed,
                                                       _Float16* __restrict__ Ef16) {
  size_t base = ((size_t)blockIdx.x * 256 + threadIdx.x) * 8;
  float4 v0 = *(const float4*)(embed + base);
  float4 v1 = *(const float4*)(embed + base + 4);
  half8 h;
  h[0] = (_Float16)v0.x; h[1] = (_Float16)v0.y; h[2] = (_Float16)v0.z; h[3] = (_Float16)v0.w;
  h[4] = (_Float16)v1.x; h[5] = (_Float16)v1.y; h[6] = (_Float16)v1.z; h[7] = (_Float16)v1.w;
  *(half8*)(Ef16 + base) = h;
}

// ---------------- fused 8-stage RVQ: LDS residual + barrier-free screen ----------
// Block owns 64 rows for all 8 stages; exact f32 residual lives in LDS [64][132]
// (2-way-free banking). Screen B-fragments are loaded per-lane from the L2-hot
// f16 codebook with 1-chunk register prefetch -> ZERO barriers in the chunk
// loop (kills the gld_lds vmcnt+barrier drain that stalled rounds 0-2).
// Fixup: round-2-validated batched block-local exact scan (same fmaf chain
// order, 2.0f*acc-enorm, lowest-index ties), resid read from LDS, codebook
// staged in the XOR-swizzled FS tile. VGPR ~104 < 128 -> no spill at any
// allocator occupancy target (the r3/r4 failure mode).
__global__ __launch_bounds__(256, 2) void rvq_fused(
    const float* __restrict__ x,          // [M_TOTAL][DDIM] f32
    const float* __restrict__ embed,      // [NQ][KCODES][DDIM] f32
    const _Float16* __restrict__ Ef16,    // [NQ][KCODES][DDIM] f16 row-major
    const float* __restrict__ enorm,      // [NQ][KCODES]
    int* __restrict__ codes)              // [NQ][M_TOTAL]
{
  __shared__ __attribute__((aligned(16))) float resid[RROWS][132];   // 33792 B
  __shared__ __attribute__((aligned(16))) float FS[RROWS * 128];     // 32768 B
  __shared__ float redv1[RROWS * 2];
  __shared__ float redv2[RROWS * 2];
  __shared__ int   redi1[RROWS * 2];
  __shared__ int   bcode[RROWS];
  __shared__ int   frows[RROWS];
  __shared__ int   fcnt;

  const int tid = threadIdx.x;
  const int wv = tid >> 6;
  const int lane = tid & 63;
  const int l15 = lane & 15;
  const int q = lane >> 4;
  const int rw = wv & 1;          // row-half of the 2x2 wave grid
  const int cw = wv >> 1;         // code-half (16 codes each per chunk)
  const int row_base = blockIdx.x * RROWS;

  // ---- x -> LDS residual (once) ----
  #pragma unroll
  for (int it = 0; it < 8; ++it) {
    int idx = it * 256 + tid;
    int r = idx >> 5, f4 = idx & 31;
    *(float4*)(&resid[r][f4 * 4]) = *(const float4*)(x + (size_t)(row_base + r) * DDIM + f4 * 4);
  }

  for (int st = 0; st < NQ; ++st) {
    const _Float16* EfS = Ef16 + (size_t)st * KCODES * DDIM;
    const float* enS = enorm + (size_t)st * KCODES;
    const float* embS = embed + (size_t)st * KCODES * DDIM;

    if (tid == 0) fcnt = 0;
    __syncthreads();              // S0: residual ready; fcnt reset ordered

    // ---- f16 A-frags from LDS residual: af[rt][kc], rows rw*32+rt*16+l15 ----
    half8 af[2][4];
    #pragma unroll
    for (int rt = 0; rt < 2; ++rt) {
      const float* pa = &resid[rw * 32 + rt * 16 + l15][0];
      #pragma unroll
      for (int kc = 0; kc < 4; ++kc) {
        float4 x0 = *(const float4*)(pa + kc * 32 + q * 8);
        float4 x1 = *(const float4*)(pa + kc * 32 + q * 8 + 4);
        half8 h;
        h[0] = (_Float16)x0.x; h[1] = (_Float16)x0.y; h[2] = (_Float16)x0.z; h[3] = (_Float16)x0.w;
        h[4] = (_Float16)x1.x; h[5] = (_Float16)x1.y; h[6] = (_Float16)x1.z; h[7] = (_Float16)x1.w;
        af[rt][kc] = h;
      }
    }

    // ---- barrier-free screen: per-lane B from L2, 1-chunk register prefetch ----
    // lane's code this chunk: c = cc*32 + cw*16 + l15; per kc a 16B fragment at
    // halfs offset c*128 + kc*32 + q*8 (matches A's k slicing).
    const _Float16* bp = EfS + (size_t)(cw * 16 + l15) * DDIM + q * 8;
    half8 bA[2][4];               // [buf][kc] -- cc loop fully unrolled => static idx
    #pragma unroll
    for (int kc = 0; kc < 4; ++kc) bA[0][kc] = *(const half8*)(bp + kc * 32);
    float enr = enS[cw * 16 + l15];

    float v1[8], v2[8];
    int i1[8];
    #pragma unroll
    for (int sI = 0; sI < 8; ++sI) { v1[sI] = -3.0e38f; v2[sI] = -3.0e38f; i1[sI] = 0x7fffffff; }

    #pragma unroll
    for (int cc = 0; cc < SNCH; ++cc) {
      const int cur = cc & 1;
      if (cc + 1 < SNCH) {        // prefetch next chunk's B into the other buffer
        const _Float16* bn = bp + (size_t)(cc + 1) * SNC * DDIM;
        #pragma unroll
        for (int kc = 0; kc < 4; ++kc) bA[cur ^ 1][kc] = *(const half8*)(bn + kc * 32);
      }
      float nh = -0.5f * enr;     // folded: d = dot - ||e||^2/2 = ref_dist/2 (validated)
      if (cc + 1 < SNCH) enr = enS[(cc + 1) * SNC + cw * 16 + l15];

      f32x4 acc0 = {nh, nh, nh, nh};
      f32x4 acc1 = {nh, nh, nh, nh};
      #pragma unroll
      for (int kc = 0; kc < 4; ++kc) {
        acc0 = __builtin_amdgcn_mfma_f32_16x16x32_f16(af[0][kc], bA[cur][kc], acc0, 0, 0, 0);
        acc1 = __builtin_amdgcn_mfma_f32_16x16x32_f16(af[1][kc], bA[cur][kc], acc1, 0, 0, 0);
      }

      // top-2 epilogue (med3 second-max; codes ascend -> strict > keeps first)
      const int cgi = cc * SNC + cw * 16 + l15;
      #pragma unroll
      for (int reg = 0; reg < 4; ++reg) {
        float d0 = acc0[reg];
        v2[reg] = __builtin_amdgcn_fmed3f(d0, v1[reg], v2[reg]);
        if (d0 > v1[reg]) i1[reg] = cgi;
        v1[reg] = fmaxf(v1[reg], d0);
        float d1 = acc1[reg];
        v2[4 + reg] = __builtin_amdgcn_fmed3f(d1, v1[4 + reg], v2[4 + reg]);
        if (d1 > v1[4 + reg]) i1[4 + reg] = cgi;
        v1[4 + reg] = fmaxf(v1[4 + reg], d1);
      }
    }

    // ---- merge top-2 across the 16 l15-lanes sharing each row (disjoint codes) ----
    #pragma unroll
    for (int sI = 0; sI < 8; ++sI) {
      #pragma unroll
      for (int off = 1; off < 16; off <<= 1) {
        float ov1 = __shfl_xor(v1[sI], off);
        int   oi1 = __shfl_xor(i1[sI], off);
        float ov2 = __shfl_xor(v2[sI], off);
        if (ov1 > v1[sI] || (ov1 == v1[sI] && oi1 < i1[sI])) {
          float nv2 = fmaxf(v1[sI], ov2);
          v1[sI] = ov1; i1[sI] = oi1; v2[sI] = nv2;
        } else {
          v2[sI] = fmaxf(v2[sI], ov1);
        }
      }
    }
    if (l15 == 0) {
      #pragma unroll
      for (int sI = 0; sI < 8; ++sI) {
        int row = rw * 32 + (sI >> 2) * 16 + q * 4 + (sI & 3);
        redv1[row * 2 + cw] = v1[sI];
        redi1[row * 2 + cw] = i1[sI];
        redv2[row * 2 + cw] = v2[sI];
      }
    }
    __syncthreads();              // S2

    // ---- final per-row merge (2 code-groups), flag into block-local list ----
    if (tid < RROWS) {
      float a1 = redv1[tid * 2], a2 = redv2[tid * 2];
      int ai = redi1[tid * 2];
      float b1v = redv1[tid * 2 + 1], b2v = redv2[tid * 2 + 1];
      int bi = redi1[tid * 2 + 1];
      float bv1, bv2; int bidx;
      if (b1v > a1 || (b1v == a1 && bi < ai)) {
        bv1 = b1v; bidx = bi; bv2 = fmaxf(a1, b2v);
      } else {
        bv1 = a1; bidx = ai; bv2 = fmaxf(b1v, a2);
      }
      bcode[tid] = bidx;
      if (bv1 - bv2 <= TAU * 0.5f) {       // screen dist scale is ref/2
        int p = atomicAdd(&fcnt, 1);
        frows[p] = tid;
      }
    }
    __syncthreads();              // S3
    const int nf = fcnt;
    __syncthreads();              // S3b: all read nf before anyone can reset it

    // ---- batched block-local exact fixup (round-2-validated arithmetic) ----
    for (int b0 = 0; b0 < nf; b0 += FB) {
      const int nb = min(FB, nf - b0);
      const int ja = wv;          // rows this wave handles
      const int jb = wv + 4;
      const int rja = (ja < nb) ? frows[b0 + ja] : 0;
      const int rjb = (jb < nb) ? frows[b0 + jb] : 0;
      float bva = -3.0e38f, bvb = -3.0e38f;
      int   bia = 0x7fffffff, bib = 0x7fffffff;

      for (int ch = 0; ch < 16; ++ch) {
        // stage 64 codes x 128 f32 into swizzled FS (coalesced global reads)
        #pragma unroll
        for (int it = 0; it < 8; ++it) {
          int idx = it * 256 + tid;
          int c = idx >> 5, f4 = idx & 31;
          *fsf4(FS, c, f4) = *(const float4*)(embS + (size_t)(ch * 64 + c) * DDIM + f4 * 4);
        }
        __syncthreads();

        const int c = ch * 64 + lane;
        const float en = enS[c];
        if (ja < nb) {
          float a = 0.f;
          #pragma unroll 4
          for (int k4 = 0; k4 < 32; ++k4) {
            float4 rv = *(const float4*)(&resid[rja][k4 * 4]);   // LDS broadcast
            float4 e4 = *fsf4(FS, lane, k4);
            a = fmaf(rv.x, e4.x, a); a = fmaf(rv.y, e4.y, a);
            a = fmaf(rv.z, e4.z, a); a = fmaf(rv.w, e4.w, a);
          }
          float dd = 2.0f * a - en;
          if (dd > bva) { bva = dd; bia = c; }   // c ascends with ch -> keeps lowest
        }
        if (jb < nb) {
          float a = 0.f;
          #pragma unroll 4
          for (int k4 = 0; k4 < 32; ++k4) {
            float4 rv = *(const float4*)(&resid[rjb][k4 * 4]);
            float4 e4 = *fsf4(FS, lane, k4);
            a = fmaf(rv.x, e4.x, a); a = fmaf(rv.y, e4.y, a);
            a = fmaf(rv.z, e4.z, a); a = fmaf(rv.w, e4.w, a);
          }
          float dd = 2.0f * a - en;
          if (dd > bvb) { bvb = dd; bib = c; }
        }
        __syncthreads();          // FS reusable next chunk
      }

      // wave-level argmax (lowest-index tie-break); wave covered all 1024 codes
      if (ja < nb) {
        float bv = bva; int bi = bia;
        #pragma unroll
        for (int off = 32; off > 0; off >>= 1) {
          float o = __shfl_down(bv, off);
          int oi = __shfl_down(bi, off);
          if (o > bv || (o == bv && oi < bi)) { bv = o; bi = oi; }
        }
        if (lane == 0) bcode[rja] = bi;
      }
      if (jb < nb) {
        float bv = bvb; int bi = bib;
        #pragma unroll
        for (int off = 32; off > 0; off >>= 1) {
          float o = __shfl_down(bv, off);
          int oi = __shfl_down(bi, off);
          if (o > bv || (o == bv && oi < bi)) { bv = o; bi = oi; }
        }
        if (lane == 0) bcode[rjb] = bi;
      }
      __syncthreads();            // bcode updates visible
    }

    // ---- codes out + exact f32 residual update in LDS (final codes) ----
    if (tid < RROWS) codes[(size_t)st * M_TOTAL + row_base + tid] = bcode[tid];
    if (st < NQ - 1) {
      #pragma unroll
      for (int it = 0; it < 8; ++it) {
        int idx = it * 256 + tid;
        int r = idx >> 5, f4 = idx & 31;
        float4 e = *(const float4*)(embS + (size_t)bcode[r] * DDIM + f4 * 4);
        float4 a = *(const float4*)(&resid[r][f4 * 4]);
        a.x -= e.x; a.y -= e.y; a.z -= e.z; a.w -= e.w;
        *(float4*)(&resid[r][f4 * 4]) = a;   // owner-exclusive (r,f4)
      }
    }
    // next stage's S0 orders the resid update vs the next A-frag reads
  }
}

// ================= fallback: round-2 verified exact-fp32 kernel =================
#define F_NCHUNK  256
#define F_KC      16
#define F_AS_STRIDE 68
#define F_ES_STRIDE 260

__global__ __launch_bounds__(256, 3) void rvq_stage_kernel(
    const float* __restrict__ rin, float* __restrict__ rout,
    const float* __restrict__ embed, const float* __restrict__ enorm,
    int* __restrict__ codes)
{
  __shared__ float smem[DDIM * F_AS_STRIDE + F_KC * F_ES_STRIDE + F_NCHUNK];
  float* As  = smem;
  float* Es  = smem + DDIM * F_AS_STRIDE;
  float* Ens = Es + F_KC * F_ES_STRIDE;
  float* red_v = Es;
  int*   red_i = (int*)(Es + 64 * 33);
  int*   bcode = (int*)(Es + 2 * 64 * 33);

  const int tid = threadIdx.x;
  const int tx = tid & 31;
  const int ty = tid >> 5;
  const int row_base = blockIdx.x * 64;

  #pragma unroll
  for (int it = 0; it < 8; ++it) {
    int idx = it * 256 + tid;
    int r = idx >> 5, f4 = idx & 31;
    float4 v = *(const float4*)(rin + (size_t)(row_base + r) * DDIM + f4 * 4);
    As[(4 * f4 + 0) * F_AS_STRIDE + r] = v.x;
    As[(4 * f4 + 1) * F_AS_STRIDE + r] = v.y;
    As[(4 * f4 + 2) * F_AS_STRIDE + r] = v.z;
    As[(4 * f4 + 3) * F_AS_STRIDE + r] = v.w;
  }

  float best[8]; int bidx[8];
  #pragma unroll
  for (int i = 0; i < 8; ++i) { best[i] = -3.0e38f; bidx[i] = 0x7fffffff; }

  for (int nc = 0; nc < KCODES / F_NCHUNK; ++nc) {
    float acc[8][8];
    #pragma unroll
    for (int i = 0; i < 8; ++i)
      #pragma unroll
      for (int j = 0; j < 8; ++j) acc[i][j] = 0.0f;

    for (int kc = 0; kc < DDIM / F_KC; ++kc) {
      __syncthreads();
      #pragma unroll
      for (int it = 0; it < 4; ++it) {
        int idx = it * 256 + tid;
        int c = idx >> 2, f4 = idx & 3;
        float4 v = *(const float4*)(embed + (size_t)(nc * F_NCHUNK + c) * DDIM + kc * F_KC + f4 * 4);
        Es[(4 * f4 + 0) * F_ES_STRIDE + c] = v.x;
        Es[(4 * f4 + 1) * F_ES_STRIDE + c] = v.y;
        Es[(4 * f4 + 2) * F_ES_STRIDE + c] = v.z;
        Es[(4 * f4 + 3) * F_ES_STRIDE + c] = v.w;
      }
      if (kc == 0) Ens[tid] = enorm[nc * F_NCHUNK + tid];
      __syncthreads();

      const float* pa = As + kc * F_KC * F_AS_STRIDE + ty * 8;
      const float* pe = Es + 4 * tx;
      #pragma unroll 4
      for (int k = 0; k < F_KC; ++k) {
        float4 a0 = *(const float4*)(pa + k * F_AS_STRIDE);
        float4 a1 = *(const float4*)(pa + k * F_AS_STRIDE + 4);
        float4 e0 = *(const float4*)(pe + k * F_ES_STRIDE);
        float4 e1 = *(const float4*)(pe + k * F_ES_STRIDE + 128);
        float aa[8] = {a0.x, a0.y, a0.z, a0.w, a1.x, a1.y, a1.z, a1.w};
        float ee[8] = {e0.x, e0.y, e0.z, e0.w, e1.x, e1.y, e1.z, e1.w};
        #pragma unroll
        for (int i = 0; i < 8; ++i)
          #pragma unroll
          for (int j = 0; j < 8; ++j)
            acc[i][j] = fmaf(aa[i], ee[j], acc[i][j]);
      }
    }

    #pragma unroll
    for (int j = 0; j < 8; ++j) {
      int c_local = (j < 4) ? (4 * tx + j) : (128 + 4 * tx + (j - 4));
      float en = Ens[c_local];
      int cg = nc * F_NCHUNK + c_local;
      #pragma unroll
      for (int i = 0; i < 8; ++i) {
        float dist = 2.0f * acc[i][j] - en;
        if (dist > best[i] || (dist == best[i] && cg < bidx[i])) { best[i] = dist; bidx[i] = cg; }
      }
    }
  }

  __syncthreads();
  #pragma unroll
  for (int i = 0; i < 8; ++i) {
    red_v[(ty * 8 + i) * 33 + tx] = best[i];
    red_i[(ty * 8 + i) * 33 + tx] = bidx[i];
  }
  __syncthreads();
  if (tid < 64) {
    float bv = red_v[tid * 33]; int bi = red_i[tid * 33];
    #pragma unroll
    for (int t = 1; t < 32; ++t) {
      float v = red_v[tid * 33 + t]; int ix = red_i[tid * 33 + t];
      if (v > bv || (v == bv && ix < bi)) { bv = v; bi = ix; }
    }
    codes[row_base + tid] = bi;
    bcode[tid] = bi;
  }
  __syncthreads();
  #pragma unroll
  for (int it = 0; it < 32; ++it) {
    int idx = it * 256 + tid;
    int r = idx >> 7, d = idx & 127;
    float e = embed[(size_t)bcode[r] * DDIM + d];
    rout[(size_t)(row_base + r) * DDIM + d] = As[d * F_AS_STRIDE + r] - e;
  }
}

extern "C" void kernel_launch(void* const* d_in, const int* in_sizes, int n_in,
                              void* d_out, int out_size, void* d_ws, size_t ws_size,
                              hipStream_t stream) {
  (void)in_sizes; (void)n_in; (void)out_size;
  const float* x = (const float*)d_in[0];
  const float* embed = (const float*)d_in[1];
  int* codes = (int*)d_out;

  const size_t E16_BYTES = (size_t)NQ * KCODES * DDIM * 2;        // 2 MB f16 codebook
  const size_t EN_BYTES  = (size_t)NQ * KCODES * 4;               // 32 KB
  const size_t need = E16_BYTES + EN_BYTES + 256;

  if (ws_size >= need) {
    char* w = (char*)d_ws;
    _Float16* Ef16 = (_Float16*)w;     w += E16_BYTES;
    float* enorm   = (float*)w;

    enorm_kernel<<<dim3(NQ * KCODES / 4), dim3(256), 0, stream>>>(embed, enorm);
    esplit16_kernel<<<dim3(NQ * KCODES * DDIM / 8 / 256), dim3(256), 0, stream>>>(embed, Ef16);
    rvq_fused<<<dim3(M_TOTAL / RROWS), dim3(256), 0, stream>>>(
        x, embed, Ef16, enorm, codes);
  } else {
    // fallback: verified round-2 exact-fp32 path
    const size_t resid_elems = (size_t)M_TOTAL * DDIM;
    const bool ws_ok = ws_size >= (resid_elems + (size_t)NQ * KCODES) * sizeof(float);
    float* resid = ws_ok ? (float*)d_ws : (float*)d_in[0];
    float* enorm = ws_ok ? ((float*)d_ws + resid_elems) : (float*)d_ws;

    enorm_kernel<<<dim3(NQ * KCODES / 4), dim3(256), 0, stream>>>(embed, enorm);
    for (int q = 0; q < NQ; ++q) {
      const float* rin = (q == 0) ? x : resid;
      rvq_stage_kernel<<<dim3(M_TOTAL / 64), dim3(256), 0, stream>>>(
          rin, resid, embed + (size_t)q * KCODES * DDIM,
          enorm + (size_t)q * KCODES, codes + (size_t)q * M_TOTAL);
    }
  }
}

// Round 7
// 589.985 us; speedup vs baseline: 7.8432x; 7.8432x over previous
//
#include <hip/hip_runtime.h>

#define M_TOTAL 65536   // B*T rows
#define DDIM    128     // latent dim (GEMM K)
#define KCODES  1024    // codebook size (GEMM N)
#define NQ      8       // RVQ stages
#define RROWS   64      // rows per block -> 1024 blocks = 4/CU co-resident
#define NC      64      // codes per Es chunk (round-0 geometry, 49 us proven)
#define NCHUNKS (KCODES / NC)          // 16
#define CHUNK_B (NC * DDIM * 2)        // 16384 B per f16 chunk
#define TAU     0.15f   // margin threshold in REF dist units (validated; screen dist = ref/2)

typedef _Float16 half8 __attribute__((ext_vector_type(8)));
typedef float    f32x4 __attribute__((ext_vector_type(4)));

// direct global->LDS copy, 16 B per lane; LDS dest is wave-uniform base + lane*16
__device__ __forceinline__ void gld_lds16(const void* g, void* l) {
  __builtin_amdgcn_global_load_lds(
      (const __attribute__((address_space(1))) unsigned int*)g,
      (__attribute__((address_space(3))) unsigned int*)l, 16, 0, 0);
}

// ---------------- ||e||^2 (verified round-1 semantics) ----------------
__global__ __launch_bounds__(256) void enorm_kernel(const float* __restrict__ embed,
                                                    float* __restrict__ enorm) {
  int c = blockIdx.x * 4 + (threadIdx.x >> 6);
  int lane = threadIdx.x & 63;
  const float* e = embed + (size_t)c * DDIM;
  float v0 = e[lane];
  float v1 = e[lane + 64];
  float s = fmaf(v0, v0, v1 * v1);
  #pragma unroll
  for (int off = 32; off > 0; off >>= 1) s += __shfl_down(s, off);
  if (lane == 0) enorm[c] = s;
}

// ---------------- embed -> f16 plane, PRE-SWIZZLED for linear global_load_lds ----
// 16B block j of code c stored at block position j ^ (c&7): after a linear
// global->LDS copy the screen's 16-lane row-strided ds_read_b128 spreads over
// all bank stripes (round-2 validated).
__global__ __launch_bounds__(256) void esplit16_kernel(const float* __restrict__ embed,
                                                       _Float16* __restrict__ Ef16) {
  unsigned u = blockIdx.x * 256 + threadIdx.x;          // half8 index: ((s*1024+c)*16+j)
  size_t src = (size_t)u * 8;
  float4 v0 = *(const float4*)(embed + src);
  float4 v1 = *(const float4*)(embed + src + 4);
  half8 h;
  h[0] = (_Float16)v0.x; h[1] = (_Float16)v0.y; h[2] = (_Float16)v0.z; h[3] = (_Float16)v0.w;
  h[4] = (_Float16)v1.x; h[5] = (_Float16)v1.y; h[6] = (_Float16)v1.z; h[7] = (_Float16)v1.w;
  unsigned row = u >> 4;                                // s*1024 + c
  unsigned j   = u & 15;
  size_t dst = (size_t)row * 128 + 8 * (j ^ (row & 7)); // (row&7) == (c&7)
  *(half8*)(Ef16 + dst) = h;
}

// ---------------- fused 8-stage RVQ with exact CANDIDATE fixup ----------------
// Round-2 structure verbatim (global resid, gld_lds NC=64 dbuf screen, VGPR-64
// proven) with the full-scan fixup replaced: the screen epilogue tracks the
// index of the second-best per (lane,slot) 32-code stream (i2); after the
// chunk loop the dead Es buffer holds all 64 candidates per row (32 disjoint
// streams x top-2). Flagged rows (margin <= TAU/2 in screen units) get an
// exact f32 re-evaluation of ONLY those 64 candidates (validated fixup
// arithmetic: sequential-k fmaf chain, 2.0f*acc - enorm, lowest-index ties).
// No 512 KB FS scan -> no L2 eviction of the block's rin rows -> the update
// pass re-read hits L2 (round 0's behavior) and the ~350 us fixup tax is gone.
__global__ __launch_bounds__(256, 4) void rvq_fused(
    const float* __restrict__ x,          // [M_TOTAL][DDIM] f32
    float* __restrict__ resid,            // [M_TOTAL][DDIM] f32 workspace
    const float* __restrict__ embed,      // [NQ][KCODES][DDIM] f32
    const _Float16* __restrict__ Ef16,    // [NQ][KCODES][DDIM] f16, pre-swizzled
    const float* __restrict__ enorm,      // [NQ][KCODES]
    int* __restrict__ codes)              // [NQ][M_TOTAL]
{
  // Es double-buffer during the chunk loop; candidate table [64 rows][32
  // streams][v1,i1,v2,i2] (= 64*512 B) after it. Both exactly 32 KB.
  __shared__ __attribute__((aligned(16))) char EsU[2 * CHUNK_B];
  __shared__ float redv1[RROWS * 2];
  __shared__ float redv2[RROWS * 2];
  __shared__ int   redi1[RROWS * 2];
  __shared__ int   bcode[RROWS];
  __shared__ int   frows[RROWS];
  __shared__ int   fcnt;

  const int tid = threadIdx.x;
  const int wv = tid >> 6;
  const int lane = tid & 63;
  const int l15 = lane & 15;
  const int q = lane >> 4;
  const int rw = wv & 1;          // row-half of the 2x2 wave grid
  const int cw = wv >> 1;         // code-half
  const int row_base = blockIdx.x * RROWS;
  const int rx = cw * 32 + l15;   // B-frag row within chunk (ct=0); ct=1 adds 16
  const int xr = rx & 7;          // Es bank swizzle key
  char* const esB = EsU;

  for (int st = 0; st < NQ; ++st) {
    const _Float16* EfS = Ef16 + (size_t)st * KCODES * DDIM;
    const float* enS = enorm + (size_t)st * KCODES;
    const float* embS = embed + (size_t)st * KCODES * DDIM;
    const float* rin = (st == 0) ? x : resid;

    if (tid == 0) fcnt = 0;       // ordered before flag atomics by chunk barriers

    // ---- A-frags from global rin (round-0 pattern) ----
    half8 af[2][4];
    #pragma unroll
    for (int rt = 0; rt < 2; ++rt) {
      const float* pa = rin + (size_t)(row_base + rw * 32 + rt * 16 + l15) * DDIM;
      #pragma unroll
      for (int kc = 0; kc < 4; ++kc) {
        float4 x0 = *(const float4*)(pa + kc * 32 + q * 8);
        float4 x1 = *(const float4*)(pa + kc * 32 + q * 8 + 4);
        half8 h;
        h[0] = (_Float16)x0.x; h[1] = (_Float16)x0.y; h[2] = (_Float16)x0.z; h[3] = (_Float16)x0.w;
        h[4] = (_Float16)x1.x; h[5] = (_Float16)x1.y; h[6] = (_Float16)x1.z; h[7] = (_Float16)x1.w;
        af[rt][kc] = h;
      }
    }

    // ---- prologue: stage chunk 0 (linear gld_lds == pre-swizzled layout) ----
    {
      const char* g = (const char*)EfS;
      #pragma unroll
      for (int it = 0; it < 4; ++it) {
        const int off = it * 4096 + wv * 1024;
        gld_lds16(g + off + lane * 16, esB + off);
      }
    }
    float enr0 = enS[cw * 32 + l15];
    float enr1 = enS[cw * 32 + 16 + l15];
    __syncthreads();              // vmcnt drained; chunk 0 ready

    float v1[8], v2[8];
    int i1[8], i2[8];
    #pragma unroll
    for (int sI = 0; sI < 8; ++sI) {
      v1[sI] = -3.0e38f; v2[sI] = -3.0e38f;
      i1[sI] = 0x7fffffff; i2[sI] = 0x7fffffff;
    }

    for (int cc = 0; cc < NCHUNKS; ++cc) {
      const int cur = cc & 1;
      if (cc + 1 < NCHUNKS) {     // prefetch next chunk (full-chunk latency window)
        const char* g = (const char*)EfS + (size_t)(cc + 1) * CHUNK_B;
        char* l = esB + (cur ^ 1) * CHUNK_B;
        #pragma unroll
        for (int it = 0; it < 4; ++it) {
          const int off = it * 4096 + wv * 1024;
          gld_lds16(g + off + lane * 16, l + off);
        }
      }
      float nh0 = -0.5f * enr0;   // folded: d = dot - ||e||^2/2 = ref_dist/2 (validated)
      float nh1 = -0.5f * enr1;
      if (cc + 1 < NCHUNKS) {     // pipeline next chunk's enorm
        enr0 = enS[(cc + 1) * NC + cw * 32 + l15];
        enr1 = enS[(cc + 1) * NC + cw * 32 + 16 + l15];
      }
      f32x4 acc[2][2];
      #pragma unroll
      for (int rt = 0; rt < 2; ++rt) {
        acc[rt][0] = (f32x4){nh0, nh0, nh0, nh0};
        acc[rt][1] = (f32x4){nh1, nh1, nh1, nh1};
      }

      const char* eb = esB + cur * CHUNK_B;
      #pragma unroll
      for (int kc = 0; kc < 4; ++kc) {
        const int jswz = 16 * ((kc * 4 + q) ^ xr);
        half8 bf0 = *(const half8*)(eb + rx * 256 + jswz);
        half8 bf1 = *(const half8*)(eb + (rx + 16) * 256 + jswz);
        #pragma unroll
        for (int rt = 0; rt < 2; ++rt) {
          acc[rt][0] = __builtin_amdgcn_mfma_f32_16x16x32_f16(af[rt][kc], bf0, acc[rt][0], 0, 0, 0);
          acc[rt][1] = __builtin_amdgcn_mfma_f32_16x16x32_f16(af[rt][kc], bf1, acc[rt][1], 0, 0, 0);
        }
      }

      // top-2 epilogue with SECOND-INDEX tracking (candidate pool for fixup).
      // Codes ascend -> strict > keeps first occurrence; i2 uses OLD v2/i1.
      #pragma unroll
      for (int ct = 0; ct < 2; ++ct) {
        const int cgi = cc * NC + cw * 32 + ct * 16 + l15;
        #pragma unroll
        for (int rt = 0; rt < 2; ++rt)
          #pragma unroll
          for (int reg = 0; reg < 4; ++reg) {
            float d = acc[rt][ct][reg];
            int s = rt * 4 + reg;
            bool g1 = d > v1[s];
            bool g2 = d > v2[s];
            i2[s] = g1 ? i1[s] : (g2 ? cgi : i2[s]);
            v2[s] = __builtin_amdgcn_fmed3f(d, v1[s], v2[s]);
            i1[s] = g1 ? cgi : i1[s];
            v1[s] = fmaxf(v1[s], d);
          }
      }
      __syncthreads();            // next buffer staged + this buffer reusable
    }
    // after the final barrier all Es reads are done -> EsU becomes cand table

    // ---- candidate dump: per-stream top-2 (value,index) pairs, 16 B/stream ----
    {
      #pragma unroll
      for (int sI = 0; sI < 8; ++sI) {
        int row = rw * 32 + (sI >> 2) * 16 + q * 4 + (sI & 3);
        char* p = EsU + row * 512 + (cw * 16 + l15) * 16;
        *(float*)(p)      = v1[sI];
        *(int*)  (p + 4)  = i1[sI];
        *(float*)(p + 8)  = v2[sI];
        *(int*)  (p + 12) = i2[sI];
      }
    }

    // ---- merge top-2 VALUES across the 16 l15-lanes (disjoint codes) ----
    #pragma unroll
    for (int sI = 0; sI < 8; ++sI) {
      #pragma unroll
      for (int off = 1; off < 16; off <<= 1) {
        float ov1 = __shfl_xor(v1[sI], off);
        int   oi1 = __shfl_xor(i1[sI], off);
        float ov2 = __shfl_xor(v2[sI], off);
        if (ov1 > v1[sI] || (ov1 == v1[sI] && oi1 < i1[sI])) {
          float nv2 = fmaxf(v1[sI], ov2);
          v1[sI] = ov1; i1[sI] = oi1; v2[sI] = nv2;
        } else {
          v2[sI] = fmaxf(v2[sI], ov1);
        }
      }
    }
    if (l15 == 0) {
      #pragma unroll
      for (int sI = 0; sI < 8; ++sI) {
        int row = rw * 32 + (sI >> 2) * 16 + q * 4 + (sI & 3);
        redv1[row * 2 + cw] = v1[sI];
        redi1[row * 2 + cw] = i1[sI];
        redv2[row * 2 + cw] = v2[sI];
      }
    }
    __syncthreads();              // cand dump + red writes visible

    // ---- final per-row merge (2 code-groups), flag into block-local list ----
    if (tid < RROWS) {
      float a1 = redv1[tid * 2], a2 = redv2[tid * 2];
      int ai = redi1[tid * 2];
      float b1v = redv1[tid * 2 + 1], b2v = redv2[tid * 2 + 1];
      int bi = redi1[tid * 2 + 1];
      float bv1, bv2; int bidx;
      if (b1v > a1 || (b1v == a1 && bi < ai)) {
        bv1 = b1v; bidx = bi; bv2 = fmaxf(a1, b2v);
      } else {
        bv1 = a1; bidx = ai; bv2 = fmaxf(b1v, a2);
      }
      bcode[tid] = bidx;
      if (bv1 - bv2 <= TAU * 0.5f) {       // screen dist scale is ref/2
        int p = atomicAdd(&fcnt, 1);
        frows[p] = tid;
      }
    }
    __syncthreads();              // flags + bcode visible
    const int nf = fcnt;

    // ---- exact candidate fixup: one wave per flagged row, lane per candidate ----
    // Validated fixup arithmetic: sequential-k fmaf chain (x,y,z,w ascending),
    // dd = 2.0f*acc - enorm, argmax with lowest-index tie-break.
    for (int f = wv; f < nf; f += 4) {
      const int r = frows[f];
      const char* cp = EsU + r * 512 + (lane >> 1) * 16 + (lane & 1) * 8;
      const int c = *(const int*)(cp + 4);           // stream top-1 or top-2 index
      const float* rv = rin + (size_t)(row_base + r) * DDIM;
      const float* ev = embS + (size_t)c * DDIM;
      float a = 0.f;
      #pragma unroll 4
      for (int k4 = 0; k4 < 32; ++k4) {
        float4 rr = *(const float4*)(rv + k4 * 4);   // wave-uniform (L1 broadcast)
        float4 e4 = *(const float4*)(ev + k4 * 4);   // per-lane code row (L2-hot)
        a = fmaf(rr.x, e4.x, a); a = fmaf(rr.y, e4.y, a);
        a = fmaf(rr.z, e4.z, a); a = fmaf(rr.w, e4.w, a);
      }
      float bv = 2.0f * a - enS[c];
      int bi = c;
      #pragma unroll
      for (int off = 32; off > 0; off >>= 1) {
        float o = __shfl_down(bv, off);
        int oi = __shfl_down(bi, off);
        if (o > bv || (o == bv && oi < bi)) { bv = o; bi = oi; }
      }
      if (lane == 0) bcode[r] = bi;
    }
    __syncthreads();              // corrected bcode visible

    // ---- codes out + exact f32 residual update (final codes; round-2 verbatim) ----
    if (tid < RROWS) codes[(size_t)st * M_TOTAL + row_base + tid] = bcode[tid];
    if (st < NQ - 1) {
      #pragma unroll
      for (int it = 0; it < 8; ++it) {
        int idx = it * 256 + tid;
        int r = idx >> 5, f4 = idx & 31;
        float4 e = *(const float4*)(embS + (size_t)bcode[r] * DDIM + f4 * 4);
        float4 a = *(const float4*)(rin + (size_t)(row_base + r) * DDIM + f4 * 4);
        float4 o;
        o.x = a.x - e.x; o.y = a.y - e.y; o.z = a.z - e.z; o.w = a.w - e.w;
        *(float4*)(resid + (size_t)(row_base + r) * DDIM + f4 * 4) = o;
      }
    }
    __syncthreads();              // resid drained; frows/bcode/EsU free for next stage
  }
}

// ================= fallback: round-2 verified exact-fp32 kernel =================
#define F_NCHUNK  256
#define F_KC      16
#define F_AS_STRIDE 68
#define F_ES_STRIDE 260

__global__ __launch_bounds__(256, 3) void rvq_stage_kernel(
    const float* __restrict__ rin, float* __restrict__ rout,
    const float* __restrict__ embed, const float* __restrict__ enorm,
    int* __restrict__ codes)
{
  __shared__ float smem[DDIM * F_AS_STRIDE + F_KC * F_ES_STRIDE + F_NCHUNK];
  float* As  = smem;
  float* Es  = smem + DDIM * F_AS_STRIDE;
  float* Ens = Es + F_KC * F_ES_STRIDE;
  float* red_v = Es;
  int*   red_i = (int*)(Es + 64 * 33);
  int*   bcode = (int*)(Es + 2 * 64 * 33);

  const int tid = threadIdx.x;
  const int tx = tid & 31;
  const int ty = tid >> 5;
  const int row_base = blockIdx.x * 64;

  #pragma unroll
  for (int it = 0; it < 8; ++it) {
    int idx = it * 256 + tid;
    int r = idx >> 5, f4 = idx & 31;
    float4 v = *(const float4*)(rin + (size_t)(row_base + r) * DDIM + f4 * 4);
    As[(4 * f4 + 0) * F_AS_STRIDE + r] = v.x;
    As[(4 * f4 + 1) * F_AS_STRIDE + r] = v.y;
    As[(4 * f4 + 2) * F_AS_STRIDE + r] = v.z;
    As[(4 * f4 + 3) * F_AS_STRIDE + r] = v.w;
  }

  float best[8]; int bidx[8];
  #pragma unroll
  for (int i = 0; i < 8; ++i) { best[i] = -3.0e38f; bidx[i] = 0x7fffffff; }

  for (int nc = 0; nc < KCODES / F_NCHUNK; ++nc) {
    float acc[8][8];
    #pragma unroll
    for (int i = 0; i < 8; ++i)
      #pragma unroll
      for (int j = 0; j < 8; ++j) acc[i][j] = 0.0f;

    for (int kc = 0; kc < DDIM / F_KC; ++kc) {
      __syncthreads();
      #pragma unroll
      for (int it = 0; it < 4; ++it) {
        int idx = it * 256 + tid;
        int c = idx >> 2, f4 = idx & 3;
        float4 v = *(const float4*)(embed + (size_t)(nc * F_NCHUNK + c) * DDIM + kc * F_KC + f4 * 4);
        Es[(4 * f4 + 0) * F_ES_STRIDE + c] = v.x;
        Es[(4 * f4 + 1) * F_ES_STRIDE + c] = v.y;
        Es[(4 * f4 + 2) * F_ES_STRIDE + c] = v.z;
        Es[(4 * f4 + 3) * F_ES_STRIDE + c] = v.w;
      }
      if (kc == 0) Ens[tid] = enorm[nc * F_NCHUNK + tid];
      __syncthreads();

      const float* pa = As + kc * F_KC * F_AS_STRIDE + ty * 8;
      const float* pe = Es + 4 * tx;
      #pragma unroll 4
      for (int k = 0; k < F_KC; ++k) {
        float4 a0 = *(const float4*)(pa + k * F_AS_STRIDE);
        float4 a1 = *(const float4*)(pa + k * F_AS_STRIDE + 4);
        float4 e0 = *(const float4*)(pe + k * F_ES_STRIDE);
        float4 e1 = *(const float4*)(pe + k * F_ES_STRIDE + 128);
        float aa[8] = {a0.x, a0.y, a0.z, a0.w, a1.x, a1.y, a1.z, a1.w};
        float ee[8] = {e0.x, e0.y, e0.z, e0.w, e1.x, e1.y, e1.z, e1.w};
        #pragma unroll
        for (int i = 0; i < 8; ++i)
          #pragma unroll
          for (int j = 0; j < 8; ++j)
            acc[i][j] = fmaf(aa[i], ee[j], acc[i][j]);
      }
    }

    #pragma unroll
    for (int j = 0; j < 8; ++j) {
      int c_local = (j < 4) ? (4 * tx + j) : (128 + 4 * tx + (j - 4));
      float en = Ens[c_local];
      int cg = nc * F_NCHUNK + c_local;
      #pragma unroll
      for (int i = 0; i < 8; ++i) {
        float dist = 2.0f * acc[i][j] - en;
        if (dist > best[i] || (dist == best[i] && cg < bidx[i])) { best[i] = dist; bidx[i] = cg; }
      }
    }
  }

  __syncthreads();
  #pragma unroll
  for (int i = 0; i < 8; ++i) {
    red_v[(ty * 8 + i) * 33 + tx] = best[i];
    red_i[(ty * 8 + i) * 33 + tx] = bidx[i];
  }
  __syncthreads();
  if (tid < 64) {
    float bv = red_v[tid * 33]; int bi = red_i[tid * 33];
    #pragma unroll
    for (int t = 1; t < 32; ++t) {
      float v = red_v[tid * 33 + t]; int ix = red_i[tid * 33 + t];
      if (v > bv || (v == bv && ix < bi)) { bv = v; bi = ix; }
    }
    codes[row_base + tid] = bi;
    bcode[tid] = bi;
  }
  __syncthreads();
  #pragma unroll
  for (int it = 0; it < 32; ++it) {
    int idx = it * 256 + tid;
    int r = idx >> 7, d = idx & 127;
    float e = embed[(size_t)bcode[r] * DDIM + d];
    rout[(size_t)(row_base + r) * DDIM + d] = As[d * F_AS_STRIDE + r] - e;
  }
}

extern "C" void kernel_launch(void* const* d_in, const int* in_sizes, int n_in,
                              void* d_out, int out_size, void* d_ws, size_t ws_size,
                              hipStream_t stream) {
  (void)in_sizes; (void)n_in; (void)out_size;
  const float* x = (const float*)d_in[0];
  const float* embed = (const float*)d_in[1];
  int* codes = (int*)d_out;

  const size_t R_BYTES   = (size_t)M_TOTAL * DDIM * 4;            // 32 MB f32 residual
  const size_t E16_BYTES = (size_t)NQ * KCODES * DDIM * 2;        // 2 MB f16 codebook
  const size_t EN_BYTES  = (size_t)NQ * KCODES * 4;               // 32 KB
  const size_t need = R_BYTES + E16_BYTES + EN_BYTES + 256;

  if (ws_size >= need) {
    char* w = (char*)d_ws;
    float* resid   = (float*)w;        w += R_BYTES;
    _Float16* Ef16 = (_Float16*)w;     w += E16_BYTES;
    float* enorm   = (float*)w;

    enorm_kernel<<<dim3(NQ * KCODES / 4), dim3(256), 0, stream>>>(embed, enorm);
    esplit16_kernel<<<dim3(NQ * KCODES * DDIM / 8 / 256), dim3(256), 0, stream>>>(embed, Ef16);
    rvq_fused<<<dim3(M_TOTAL / RROWS), dim3(256), 0, stream>>>(
        x, resid, embed, Ef16, enorm, codes);
  } else {
    // fallback: verified round-2 exact-fp32 path
    const size_t resid_elems = (size_t)M_TOTAL * DDIM;
    const bool ws_ok = ws_size >= (resid_elems + (size_t)NQ * KCODES) * sizeof(float);
    float* resid = ws_ok ? (float*)d_ws : (float*)d_in[0];
    float* enorm = ws_ok ? ((float*)d_ws + resid_elems) : (float*)d_ws;

    enorm_kernel<<<dim3(NQ * KCODES / 4), dim3(256), 0, stream>>>(embed, enorm);
    for (int q = 0; q < NQ; ++q) {
      const float* rin = (q == 0) ? x : resid;
      rvq_stage_kernel<<<dim3(M_TOTAL / 64), dim3(256), 0, stream>>>(
          rin, resid, embed + (size_t)q * KCODES * DDIM,
          enorm + (size_t)q * KCODES, codes + (size_t)q * M_TOTAL);
    }
  }
}

// Round 8
// 504.746 us; speedup vs baseline: 9.1677x; 1.1689x over previous
//
#include <hip/hip_runtime.h>

#define M_TOTAL 65536   // B*T rows
#define DDIM    128     // latent dim (GEMM K)
#define KCODES  1024    // codebook size (GEMM N)
#define NQ      8       // RVQ stages
#define RROWS   64      // rows per block -> 1024 blocks, 3/CU co-resident
#define NC      64      // codes per Es chunk
#define NCHUNKS (KCODES / NC)          // 16
#define CHUNK_B (NC * DDIM * 2)        // 16384 B per f16 chunk (single buffer)
#define TAU     0.15f   // margin threshold in REF dist units (validated; screen dist = ref/2)

typedef _Float16 half8 __attribute__((ext_vector_type(8)));
typedef float    f32x4 __attribute__((ext_vector_type(4)));

// direct global->LDS copy, 16 B per lane; LDS dest is wave-uniform base + lane*16
__device__ __forceinline__ void gld_lds16(const void* g, void* l) {
  __builtin_amdgcn_global_load_lds(
      (const __attribute__((address_space(1))) unsigned int*)g,
      (__attribute__((address_space(3))) unsigned int*)l, 16, 0, 0);
}

// ---------------- ||e||^2 (verified round-1 semantics) ----------------
__global__ __launch_bounds__(256) void enorm_kernel(const float* __restrict__ embed,
                                                    float* __restrict__ enorm) {
  int c = blockIdx.x * 4 + (threadIdx.x >> 6);
  int lane = threadIdx.x & 63;
  const float* e = embed + (size_t)c * DDIM;
  float v0 = e[lane];
  float v1 = e[lane + 64];
  float s = fmaf(v0, v0, v1 * v1);
  #pragma unroll
  for (int off = 32; off > 0; off >>= 1) s += __shfl_down(s, off);
  if (lane == 0) enorm[c] = s;
}

// ---------------- embed -> f16 plane, PRE-SWIZZLED for linear global_load_lds ----
// 16B block j of code c stored at position j ^ (c&7): after a linear global->LDS
// copy the screen's ds_read_b128 pattern runs at the b128 bank floor (validated r7).
__global__ __launch_bounds__(256) void esplit16_kernel(const float* __restrict__ embed,
                                                       _Float16* __restrict__ Ef16) {
  unsigned u = blockIdx.x * 256 + threadIdx.x;          // half8 index: ((s*1024+c)*16+j)
  size_t src = (size_t)u * 8;
  float4 v0 = *(const float4*)(embed + src);
  float4 v1 = *(const float4*)(embed + src + 4);
  half8 h;
  h[0] = (_Float16)v0.x; h[1] = (_Float16)v0.y; h[2] = (_Float16)v0.z; h[3] = (_Float16)v0.w;
  h[4] = (_Float16)v1.x; h[5] = (_Float16)v1.y; h[6] = (_Float16)v1.z; h[7] = (_Float16)v1.w;
  unsigned row = u >> 4;                                // s*1024 + c
  unsigned j   = u & 15;
  size_t dst = (size_t)row * 128 + 8 * (j ^ (row & 7)); // (row&7) == (c&7)
  *(half8*)(Ef16 + dst) = h;
}

// ---------------- fused 8-stage RVQ: LDS-resident residual, zero resid HBM ----
// Block owns 64 rows for all 8 stages; exact f32 residual lives in LDS [64][132]
// (528 B rows, 16B-aligned). Wave w owns rows w*16..w*16+15 and computes ALL
// 1024 codes for them (single-owner: no cw duplication). Screen: single-buffer
// Es (16 KB, pre-swizzled gld_lds) with the next-chunk issue slotted between
// the two chunk barriers, overlapped by the epilogue VALU. Candidate fixup:
// top-2 (value,index) per 64-code stream (16 streams/row -> 16 KB table
// overlaying the dead Es buffer); flagged rows get an exact f32 re-eval of
// their 32 candidates (validated arithmetic: sequential-k fmaf chain,
// 2.0f*acc - enorm, lowest-index ties). Residual update runs entirely in LDS.
// HBM: x read once + codebook first-touches + codes write.
__global__ __launch_bounds__(256, 3) void rvq_fused(
    const float* __restrict__ x,          // [M_TOTAL][DDIM] f32
    const float* __restrict__ embed,      // [NQ][KCODES][DDIM] f32
    const _Float16* __restrict__ Ef16,    // [NQ][KCODES][DDIM] f16, pre-swizzled
    const float* __restrict__ enorm,      // [NQ][KCODES]
    int* __restrict__ codes)              // [NQ][M_TOTAL]
{
  __shared__ __attribute__((aligned(16))) float resid[RROWS][132];   // 33792 B
  __shared__ __attribute__((aligned(16))) char EsU[CHUNK_B];         // 16384 B (Es / cand)
  __shared__ int bcode[RROWS];
  __shared__ int frows[RROWS];
  __shared__ int fcnt;

  const int tid = threadIdx.x;
  const int w = tid >> 6;         // wave: owns rows w*16..w*16+15
  const int lane = tid & 63;
  const int l15 = lane & 15;
  const int q = lane >> 4;
  const int row_base = blockIdx.x * RROWS;

  // ---- x -> LDS residual (once, coalesced) ----
  #pragma unroll
  for (int it = 0; it < 8; ++it) {
    int idx = it * 256 + tid;
    int r = idx >> 5, f4 = idx & 31;
    *(float4*)(&resid[r][f4 * 4]) = *(const float4*)(x + (size_t)(row_base + r) * DDIM + f4 * 4);
  }
  if (tid == 0) fcnt = 0;
  __syncthreads();

  for (int st = 0; st < NQ; ++st) {
    const _Float16* EfS = Ef16 + (size_t)st * KCODES * DDIM;
    const float* enS = enorm + (size_t)st * KCODES;
    const float* embS = embed + (size_t)st * KCODES * DDIM;

    // ---- f16 A-frags from LDS residual: A[m=l15][k=q*8+j], rows w*16+l15 ----
    half8 af[4];
    {
      const float* pa = &resid[w * 16 + l15][0];
      #pragma unroll
      for (int kc = 0; kc < 4; ++kc) {
        float4 x0 = *(const float4*)(pa + kc * 32 + q * 8);
        float4 x1 = *(const float4*)(pa + kc * 32 + q * 8 + 4);
        half8 h;
        h[0] = (_Float16)x0.x; h[1] = (_Float16)x0.y; h[2] = (_Float16)x0.z; h[3] = (_Float16)x0.w;
        h[4] = (_Float16)x1.x; h[5] = (_Float16)x1.y; h[6] = (_Float16)x1.z; h[7] = (_Float16)x1.w;
        af[kc] = h;
      }
    }

    // ---- prologue: stage chunk 0 (linear gld_lds == pre-swizzled layout) ----
    {
      const char* g = (const char*)EfS;
      #pragma unroll
      for (int it = 0; it < 4; ++it) {
        const int off = it * 4096 + w * 1024;
        gld_lds16(g + off + lane * 16, EsU + off);
      }
    }
    float enr[4];
    #pragma unroll
    for (int ct = 0; ct < 4; ++ct) enr[ct] = enS[ct * 16 + l15];
    __syncthreads();              // chunk 0 staged (vmcnt drained); A-frag reads done

    // 4 streams/thread (reg); each stream sees codes {cc*64 + ct*16 + l15},
    // ct+cc ascending -> strict > keeps lowest index (first occurrence).
    float v1[4], v2[4];
    int i1[4], i2[4];
    #pragma unroll
    for (int s = 0; s < 4; ++s) {
      v1[s] = -3.0e38f; v2[s] = -3.0e38f;
      i1[s] = 0x7fffffff; i2[s] = 0x7fffffff;
    }

    for (int cc = 0; cc < NCHUNKS; ++cc) {
      // ---- MFMA phase: dist rows q*4+reg, code cols l15 (m89 C-layout) ----
      f32x4 acc[4];
      #pragma unroll
      for (int ct = 0; ct < 4; ++ct) {
        float nh = -0.5f * enr[ct];   // folded: d = dot - ||e||^2/2 = ref_dist/2
        acc[ct] = (f32x4){nh, nh, nh, nh};
      }
      #pragma unroll
      for (int kc = 0; kc < 4; ++kc) {
        const int jswz = 16 * ((kc * 4 + q) ^ (l15 & 7));
        #pragma unroll
        for (int ct = 0; ct < 4; ++ct) {
          half8 bf = *(const half8*)(EsU + (ct * 16 + l15) * 256 + jswz);
          acc[ct] = __builtin_amdgcn_mfma_f32_16x16x32_f16(af[kc], bf, acc[ct], 0, 0, 0);
        }
      }
      __syncthreads();            // all Es reads done -> buffer overwritable

      if (cc + 1 < NCHUNKS) {     // issue next chunk; latency hides under epilogue
        const char* g = (const char*)EfS + (size_t)(cc + 1) * CHUNK_B;
        #pragma unroll
        for (int it = 0; it < 4; ++it) {
          const int off = it * 4096 + w * 1024;
          gld_lds16(g + off + lane * 16, EsU + off);
        }
        #pragma unroll
        for (int ct = 0; ct < 4; ++ct)        // enr dead after acc init
          enr[ct] = enS[(cc + 1) * NC + ct * 16 + l15];
      }

      // ---- top-2 epilogue with second-index tracking (candidate pool) ----
      #pragma unroll
      for (int ct = 0; ct < 4; ++ct) {
        const int cgi = cc * NC + ct * 16 + l15;
        #pragma unroll
        for (int reg = 0; reg < 4; ++reg) {
          float d = acc[ct][reg];
          bool g1 = d > v1[reg];
          bool g2 = d > v2[reg];
          i2[reg] = g1 ? i1[reg] : (g2 ? cgi : i2[reg]);
          v2[reg] = __builtin_amdgcn_fmed3f(d, v1[reg], v2[reg]);
          i1[reg] = g1 ? cgi : i1[reg];
          v1[reg] = fmaxf(v1[reg], d);
        }
      }
      __syncthreads();            // next chunk staged (vmcnt drained)
    }
    // Es buffer dead -> becomes candidate table [row][l15] (16 B/stream)

    // ---- candidate dump: stream (row = w*16+q*4+reg, l15) -> table ----
    #pragma unroll
    for (int reg = 0; reg < 4; ++reg) {
      const int row = w * 16 + q * 4 + reg;
      char* p = EsU + row * 256 + l15 * 16;
      *(float*)(p)      = v1[reg];
      *(int*)  (p + 4)  = i1[reg];
      *(float*)(p + 8)  = v2[reg];
      *(int*)  (p + 12) = i2[reg];
    }

    // ---- merge top-2 across the 16 l15-lanes sharing each row (disjoint codes) ----
    #pragma unroll
    for (int s = 0; s < 4; ++s) {
      #pragma unroll
      for (int off = 1; off < 16; off <<= 1) {
        float ov1 = __shfl_xor(v1[s], off);
        int   oi1 = __shfl_xor(i1[s], off);
        float ov2 = __shfl_xor(v2[s], off);
        if (ov1 > v1[s] || (ov1 == v1[s] && oi1 < i1[s])) {
          float nv2 = fmaxf(v1[s], ov2);
          v1[s] = ov1; i1[s] = oi1; v2[s] = nv2;
        } else {
          v2[s] = fmaxf(v2[s], ov1);
        }
      }
    }
    if (l15 == 0) {
      #pragma unroll
      for (int s = 0; s < 4; ++s) {
        const int row = w * 16 + q * 4 + s;
        bcode[row] = i1[s];
        if (v1[s] - v2[s] <= TAU * 0.5f) {   // screen dist scale is ref/2
          int p = atomicAdd(&fcnt, 1);
          frows[p] = row;
        }
      }
    }
    __syncthreads();              // cand table + flags + bcode visible
    const int nf = fcnt;

    // ---- exact candidate fixup: one wave per flagged row, 32 candidates ----
    // (lanes 32-63 duplicate lanes 0-31; tie-break makes duplication harmless)
    for (int f = w; f < nf; f += 4) {
      const int r = frows[f];
      const int cslot = lane & 31;
      const char* cp = EsU + r * 256 + (cslot >> 1) * 16 + (cslot & 1) * 8;
      const int c = *(const int*)(cp + 4);
      const float* rv = &resid[r][0];                // LDS, wave-uniform row
      const float* ev = embS + (size_t)c * DDIM;     // per-lane code row (L2-hot)
      float a = 0.f;
      #pragma unroll 4
      for (int k4 = 0; k4 < 32; ++k4) {
        float4 rr = *(const float4*)(rv + k4 * 4);
        float4 e4 = *(const float4*)(ev + k4 * 4);
        a = fmaf(rr.x, e4.x, a); a = fmaf(rr.y, e4.y, a);
        a = fmaf(rr.z, e4.z, a); a = fmaf(rr.w, e4.w, a);
      }
      float bv = 2.0f * a - enS[c];
      int bi = c;
      #pragma unroll
      for (int off = 32; off > 0; off >>= 1) {
        float o = __shfl_down(bv, off);
        int oi = __shfl_down(bi, off);
        if (o > bv || (o == bv && oi < bi)) { bv = o; bi = oi; }
      }
      if (lane == 0) bcode[r] = bi;
    }
    __syncthreads();              // corrected bcode visible
    if (tid == 0) fcnt = 0;       // next write behind >=1 barrier, reads done

    // ---- codes out + exact f32 residual update in LDS (final codes) ----
    if (tid < RROWS) codes[(size_t)st * M_TOTAL + row_base + tid] = bcode[tid];
    if (st < NQ - 1) {
      #pragma unroll
      for (int it = 0; it < 8; ++it) {
        int idx = it * 256 + tid;
        int r = idx >> 5, f4 = idx & 31;
        float4 e = *(const float4*)(embS + (size_t)bcode[r] * DDIM + f4 * 4);
        float4 a = *(const float4*)(&resid[r][f4 * 4]);
        a.x -= e.x; a.y -= e.y; a.z -= e.z; a.w -= e.w;
        *(float4*)(&resid[r][f4 * 4]) = a;   // owner-exclusive (r,f4)
      }
    }
    __syncthreads();              // resid update + fcnt reset ordered vs next stage
  }
}

// ================= fallback: round-2 verified exact-fp32 kernel =================
#define F_NCHUNK  256
#define F_KC      16
#define F_AS_STRIDE 68
#define F_ES_STRIDE 260

__global__ __launch_bounds__(256, 3) void rvq_stage_kernel(
    const float* __restrict__ rin, float* __restrict__ rout,
    const float* __restrict__ embed, const float* __restrict__ enorm,
    int* __restrict__ codes)
{
  __shared__ float smem[DDIM * F_AS_STRIDE + F_KC * F_ES_STRIDE + F_NCHUNK];
  float* As  = smem;
  float* Es  = smem + DDIM * F_AS_STRIDE;
  float* Ens = Es + F_KC * F_ES_STRIDE;
  float* red_v = Es;
  int*   red_i = (int*)(Es + 64 * 33);
  int*   bcode = (int*)(Es + 2 * 64 * 33);

  const int tid = threadIdx.x;
  const int tx = tid & 31;
  const int ty = tid >> 5;
  const int row_base = blockIdx.x * 64;

  #pragma unroll
  for (int it = 0; it < 8; ++it) {
    int idx = it * 256 + tid;
    int r = idx >> 5, f4 = idx & 31;
    float4 v = *(const float4*)(rin + (size_t)(row_base + r) * DDIM + f4 * 4);
    As[(4 * f4 + 0) * F_AS_STRIDE + r] = v.x;
    As[(4 * f4 + 1) * F_AS_STRIDE + r] = v.y;
    As[(4 * f4 + 2) * F_AS_STRIDE + r] = v.z;
    As[(4 * f4 + 3) * F_AS_STRIDE + r] = v.w;
  }

  float best[8]; int bidx[8];
  #pragma unroll
  for (int i = 0; i < 8; ++i) { best[i] = -3.0e38f; bidx[i] = 0x7fffffff; }

  for (int nc = 0; nc < KCODES / F_NCHUNK; ++nc) {
    float acc[8][8];
    #pragma unroll
    for (int i = 0; i < 8; ++i)
      #pragma unroll
      for (int j = 0; j < 8; ++j) acc[i][j] = 0.0f;

    for (int kc = 0; kc < DDIM / F_KC; ++kc) {
      __syncthreads();
      #pragma unroll
      for (int it = 0; it < 4; ++it) {
        int idx = it * 256 + tid;
        int c = idx >> 2, f4 = idx & 3;
        float4 v = *(const float4*)(embed + (size_t)(nc * F_NCHUNK + c) * DDIM + kc * F_KC + f4 * 4);
        Es[(4 * f4 + 0) * F_ES_STRIDE + c] = v.x;
        Es[(4 * f4 + 1) * F_ES_STRIDE + c] = v.y;
        Es[(4 * f4 + 2) * F_ES_STRIDE + c] = v.z;
        Es[(4 * f4 + 3) * F_ES_STRIDE + c] = v.w;
      }
      if (kc == 0) Ens[tid] = enorm[nc * F_NCHUNK + tid];
      __syncthreads();

      const float* pa = As + kc * F_KC * F_AS_STRIDE + ty * 8;
      const float* pe = Es + 4 * tx;
      #pragma unroll 4
      for (int k = 0; k < F_KC; ++k) {
        float4 a0 = *(const float4*)(pa + k * F_AS_STRIDE);
        float4 a1 = *(const float4*)(pa + k * F_AS_STRIDE + 4);
        float4 e0 = *(const float4*)(pe + k * F_ES_STRIDE);
        float4 e1 = *(const float4*)(pe + k * F_ES_STRIDE + 128);
        float aa[8] = {a0.x, a0.y, a0.z, a0.w, a1.x, a1.y, a1.z, a1.w};
        float ee[8] = {e0.x, e0.y, e0.z, e0.w, e1.x, e1.y, e1.z, e1.w};
        #pragma unroll
        for (int i = 0; i < 8; ++i)
          #pragma unroll
          for (int j = 0; j < 8; ++j)
            acc[i][j] = fmaf(aa[i], ee[j], acc[i][j]);
      }
    }

    #pragma unroll
    for (int j = 0; j < 8; ++j) {
      int c_local = (j < 4) ? (4 * tx + j) : (128 + 4 * tx + (j - 4));
      float en = Ens[c_local];
      int cg = nc * F_NCHUNK + c_local;
      #pragma unroll
      for (int i = 0; i < 8; ++i) {
        float dist = 2.0f * acc[i][j] - en;
        if (dist > best[i] || (dist == best[i] && cg < bidx[i])) { best[i] = dist; bidx[i] = cg; }
      }
    }
  }

  __syncthreads();
  #pragma unroll
  for (int i = 0; i < 8; ++i) {
    red_v[(ty * 8 + i) * 33 + tx] = best[i];
    red_i[(ty * 8 + i) * 33 + tx] = bidx[i];
  }
  __syncthreads();
  if (tid < 64) {
    float bv = red_v[tid * 33]; int bi = red_i[tid * 33];
    #pragma unroll
    for (int t = 1; t < 32; ++t) {
      float v = red_v[tid * 33 + t]; int ix = red_i[tid * 33 + t];
      if (v > bv || (v == bv && ix < bi)) { bv = v; bi = ix; }
    }
    codes[row_base + tid] = bi;
    bcode[tid] = bi;
  }
  __syncthreads();
  #pragma unroll
  for (int it = 0; it < 32; ++it) {
    int idx = it * 256 + tid;
    int r = idx >> 7, d = idx & 127;
    float e = embed[(size_t)bcode[r] * DDIM + d];
    rout[(size_t)(row_base + r) * DDIM + d] = As[d * F_AS_STRIDE + r] - e;
  }
}

extern "C" void kernel_launch(void* const* d_in, const int* in_sizes, int n_in,
                              void* d_out, int out_size, void* d_ws, size_t ws_size,
                              hipStream_t stream) {
  (void)in_sizes; (void)n_in; (void)out_size;
  const float* x = (const float*)d_in[0];
  const float* embed = (const float*)d_in[1];
  int* codes = (int*)d_out;

  const size_t E16_BYTES = (size_t)NQ * KCODES * DDIM * 2;        // 2 MB f16 codebook
  const size_t EN_BYTES  = (size_t)NQ * KCODES * 4;               // 32 KB
  const size_t need = E16_BYTES + EN_BYTES + 256;

  if (ws_size >= need) {
    char* w = (char*)d_ws;
    _Float16* Ef16 = (_Float16*)w;     w += E16_BYTES;
    float* enorm   = (float*)w;

    enorm_kernel<<<dim3(NQ * KCODES / 4), dim3(256), 0, stream>>>(embed, enorm);
    esplit16_kernel<<<dim3(NQ * KCODES * DDIM / 8 / 256), dim3(256), 0, stream>>>(embed, Ef16);
    rvq_fused<<<dim3(M_TOTAL / RROWS), dim3(256), 0, stream>>>(
        x, embed, Ef16, enorm, codes);
  } else {
    // fallback: verified round-2 exact-fp32 path
    const size_t resid_elems = (size_t)M_TOTAL * DDIM;
    const bool ws_ok = ws_size >= (resid_elems + (size_t)NQ * KCODES) * sizeof(float);
    float* resid = ws_ok ? (float*)d_ws : (float*)d_in[0];
    float* enorm = ws_ok ? ((float*)d_ws + resid_elems) : (float*)d_ws;

    enorm_kernel<<<dim3(NQ * KCODES / 4), dim3(256), 0, stream>>>(embed, enorm);
    for (int q = 0; q < NQ; ++q) {
      const float* rin = (q == 0) ? x : resid;
      rvq_stage_kernel<<<dim3(M_TOTAL / 64), dim3(256), 0, stream>>>(
          rin, resid, embed + (size_t)q * KCODES * DDIM,
          enorm + (size_t)q * KCODES, codes + (size_t)q * M_TOTAL);
    }
  }
}

// Round 9
// 362.179 us; speedup vs baseline: 12.7765x; 1.3936x over previous
//
#include <hip/hip_runtime.h>

#define M_TOTAL 65536   // B*T rows
#define DDIM    128     // latent dim (GEMM K)
#define KCODES  1024    // codebook size (GEMM N)
#define NQ      8       // RVQ stages
#define RROWS   64      // rows per block -> 1024 blocks, 3/CU co-resident
#define NC      64      // codes per Es chunk
#define NCHUNKS (KCODES / NC)          // 16
#define CHUNK_B (NC * DDIM * 2)        // 16384 B per f16 chunk (single buffer)
#define BIAS    320.0f  // folded into acc init: keys strictly positive (12+ sigma margin)
#define THRQ    0.106f  // screen-unit flag threshold = validated 0.075 + 0.031 quant guard

typedef _Float16 half8 __attribute__((ext_vector_type(8)));
typedef float    f32x4 __attribute__((ext_vector_type(4)));
typedef unsigned u32x2 __attribute__((ext_vector_type(2)));

__device__ __forceinline__ unsigned umx(unsigned a, unsigned b) { return a > b ? a : b; }
__device__ __forceinline__ unsigned umn(unsigned a, unsigned b) { return a < b ? a : b; }

// direct global->LDS copy, 16 B per lane; LDS dest is wave-uniform base + lane*16
__device__ __forceinline__ void gld_lds16(const void* g, void* l) {
  __builtin_amdgcn_global_load_lds(
      (const __attribute__((address_space(1))) unsigned int*)g,
      (__attribute__((address_space(3))) unsigned int*)l, 16, 0, 0);
}

// ---------------- ||e||^2 (verified round-1 semantics) ----------------
__global__ __launch_bounds__(256) void enorm_kernel(const float* __restrict__ embed,
                                                    float* __restrict__ enorm) {
  int c = blockIdx.x * 4 + (threadIdx.x >> 6);
  int lane = threadIdx.x & 63;
  const float* e = embed + (size_t)c * DDIM;
  float v0 = e[lane];
  float v1 = e[lane + 64];
  float s = fmaf(v0, v0, v1 * v1);
  #pragma unroll
  for (int off = 32; off > 0; off >>= 1) s += __shfl_down(s, off);
  if (lane == 0) enorm[c] = s;
}

// ---------------- embed -> f16 plane, PRE-SWIZZLED for linear global_load_lds ----
__global__ __launch_bounds__(256) void esplit16_kernel(const float* __restrict__ embed,
                                                       _Float16* __restrict__ Ef16) {
  unsigned u = blockIdx.x * 256 + threadIdx.x;          // half8 index: ((s*1024+c)*16+j)
  size_t src = (size_t)u * 8;
  float4 v0 = *(const float4*)(embed + src);
  float4 v1 = *(const float4*)(embed + src + 4);
  half8 h;
  h[0] = (_Float16)v0.x; h[1] = (_Float16)v0.y; h[2] = (_Float16)v0.z; h[3] = (_Float16)v0.w;
  h[4] = (_Float16)v1.x; h[5] = (_Float16)v1.y; h[6] = (_Float16)v1.z; h[7] = (_Float16)v1.w;
  unsigned row = u >> 4;                                // s*1024 + c
  unsigned j   = u & 15;
  size_t dst = (size_t)row * 128 + 8 * (j ^ (row & 7)); // (row&7) == (c&7)
  *(half8*)(Ef16 + dst) = h;
}

// ---------------- fused 8-stage RVQ: LDS residual + 2x2 grid + packed-key top-2 ----
// Residual in LDS [64][132] for all 8 stages (r8-validated: zero resid HBM).
// Screen: 2x2 wave grid (rw,cw) -> each wave reads only its 32-code half of Es
// (8 ds_read_b128/chunk, HALF of r8's 16: kills the 4x LDS B duplication).
// Top-2 tracked as packed sortable keys: dist biased positive (BIAS folded into
// MFMA acc init) -> float bits uint-comparable; key = (bits & ~1023)|(1023-cgi)
// gives branchless min/max top-2 with the exact lowest-index tie-break. Mantissa
// truncation <= 0.031 screen units -> flag threshold THRQ = 0.075(validated) +
// 0.031; mis-rankings inside the window force margin < THRQ -> exact fixup.
// Candidates: top-2 of each of 32 streams/row (16 KB table overlays dead Es);
// fixup = exact f32 dot over 64 candidates (validated chain, 2*acc-enorm).
__global__ __launch_bounds__(256, 3) void rvq_fused(
    const float* __restrict__ x,          // [M_TOTAL][DDIM] f32
    const float* __restrict__ embed,      // [NQ][KCODES][DDIM] f32
    const _Float16* __restrict__ Ef16,    // [NQ][KCODES][DDIM] f16, pre-swizzled
    const float* __restrict__ enorm,      // [NQ][KCODES]
    int* __restrict__ codes)              // [NQ][M_TOTAL]
{
  __shared__ __attribute__((aligned(16))) float resid[RROWS][132];   // 33792 B
  __shared__ __attribute__((aligned(16))) char EsU[CHUNK_B];         // 16384 B (Es / cand)
  __shared__ unsigned redk[RROWS][2][2];                             // 1024 B
  __shared__ int bcode[RROWS];
  __shared__ int frows[RROWS];
  __shared__ int fcnt;

  const int tid = threadIdx.x;
  const int wv = tid >> 6;
  const int lane = tid & 63;
  const int l15 = lane & 15;
  const int q = lane >> 4;
  const int rw = wv & 1;          // row-half of the 2x2 wave grid
  const int cw = wv >> 1;         // code-half
  const int row_base = blockIdx.x * RROWS;
  const int rx = cw * 32 + l15;   // B-frag row within chunk (ct=0); ct=1 adds 16
  const int xr = rx & 7;          // Es bank swizzle key (rx and rx+16 share it)

  // ---- x -> LDS residual (once, coalesced) ----
  #pragma unroll
  for (int it = 0; it < 8; ++it) {
    int idx = it * 256 + tid;
    int r = idx >> 5, f4 = idx & 31;
    *(float4*)(&resid[r][f4 * 4]) = *(const float4*)(x + (size_t)(row_base + r) * DDIM + f4 * 4);
  }
  if (tid == 0) fcnt = 0;
  __syncthreads();

  for (int st = 0; st < NQ; ++st) {
    const _Float16* EfS = Ef16 + (size_t)st * KCODES * DDIM;
    const float* enS = enorm + (size_t)st * KCODES;
    const float* embS = embed + (size_t)st * KCODES * DDIM;

    // ---- f16 A-frags from LDS residual: af[rt][kc], rows rw*32+rt*16+l15 ----
    half8 af[2][4];
    #pragma unroll
    for (int rt = 0; rt < 2; ++rt) {
      const float* pa = &resid[rw * 32 + rt * 16 + l15][0];
      #pragma unroll
      for (int kc = 0; kc < 4; ++kc) {
        float4 x0 = *(const float4*)(pa + kc * 32 + q * 8);
        float4 x1 = *(const float4*)(pa + kc * 32 + q * 8 + 4);
        half8 h;
        h[0] = (_Float16)x0.x; h[1] = (_Float16)x0.y; h[2] = (_Float16)x0.z; h[3] = (_Float16)x0.w;
        h[4] = (_Float16)x1.x; h[5] = (_Float16)x1.y; h[6] = (_Float16)x1.z; h[7] = (_Float16)x1.w;
        af[rt][kc] = h;
      }
    }

    // ---- prologue: stage chunk 0 (linear gld_lds == pre-swizzled layout) ----
    {
      const char* g = (const char*)EfS;
      #pragma unroll
      for (int it = 0; it < 4; ++it) {
        const int off = it * 4096 + wv * 1024;
        gld_lds16(g + off + lane * 16, EsU + off);
      }
    }
    float enr0 = enS[cw * 32 + l15];
    float enr1 = enS[cw * 32 + 16 + l15];
    __syncthreads();              // chunk 0 staged (vmcnt drained); A-frag reads done

    // 8 key-pair streams/thread: stream (rt,reg) holds row rw*32+rt*16+q*4+reg's
    // code column (cw,l15) = {cc*64 + cw*32 + ct*16 + l15}. 32 codes/stream.
    unsigned k1[8], k2[8];
    #pragma unroll
    for (int s = 0; s < 8; ++s) { k1[s] = 0u; k2[s] = 0u; }

    for (int cc = 0; cc < NCHUNKS; ++cc) {
      float nh0 = BIAS - 0.5f * enr0;  // biased: d = BIAS + dot - ||e||^2/2 > 0
      float nh1 = BIAS - 0.5f * enr1;
      if (cc + 1 < NCHUNKS) {          // pipeline next chunk's enorm
        enr0 = enS[(cc + 1) * NC + cw * 32 + l15];
        enr1 = enS[(cc + 1) * NC + cw * 32 + 16 + l15];
      }
      f32x4 acc[2][2];
      #pragma unroll
      for (int rt = 0; rt < 2; ++rt) {
        acc[rt][0] = (f32x4){nh0, nh0, nh0, nh0};
        acc[rt][1] = (f32x4){nh1, nh1, nh1, nh1};
      }

      #pragma unroll
      for (int kc = 0; kc < 4; ++kc) {
        const int jswz = 16 * ((kc * 4 + q) ^ xr);
        half8 bf0 = *(const half8*)(EsU + rx * 256 + jswz);
        half8 bf1 = *(const half8*)(EsU + (rx + 16) * 256 + jswz);
        #pragma unroll
        for (int rt = 0; rt < 2; ++rt) {
          acc[rt][0] = __builtin_amdgcn_mfma_f32_16x16x32_f16(af[rt][kc], bf0, acc[rt][0], 0, 0, 0);
          acc[rt][1] = __builtin_amdgcn_mfma_f32_16x16x32_f16(af[rt][kc], bf1, acc[rt][1], 0, 0, 0);
        }
      }
      __syncthreads();            // all Es reads done -> buffer overwritable

      if (cc + 1 < NCHUNKS) {     // issue next chunk; latency hides under epilogue
        const char* g = (const char*)EfS + (size_t)(cc + 1) * CHUNK_B;
        #pragma unroll
        for (int it = 0; it < 4; ++it) {
          const int off = it * 4096 + wv * 1024;
          gld_lds16(g + off + lane * 16, EsU + off);
        }
      }

      // ---- packed-key top-2 epilogue (distinct keys -> exact low-index ties) ----
      const unsigned revb = 1023u - (unsigned)(cc * NC + cw * 32 + l15);  // ct=0
      #pragma unroll
      for (int rt = 0; rt < 2; ++rt)
        #pragma unroll
        for (int reg = 0; reg < 4; ++reg) {
          const int s = rt * 4 + reg;
          unsigned kk0 = (__float_as_uint(acc[rt][0][reg]) & 0xFFFFFC00u) | revb;
          k2[s] = umx(umn(kk0, k1[s]), k2[s]);
          k1[s] = umx(k1[s], kk0);
          unsigned kk1 = (__float_as_uint(acc[rt][1][reg]) & 0xFFFFFC00u) | (revb - 16u);
          k2[s] = umx(umn(kk1, k1[s]), k2[s]);
          k1[s] = umx(k1[s], kk1);
        }
      __syncthreads();            // next chunk staged (vmcnt drained)
    }
    // EsU dead -> candidate table [row][cw*16+l15] = {k1,k2} (8 B/stream, 16 KB)

    // ---- candidate dump (pre-merge per-stream top-2) ----
    #pragma unroll
    for (int rt = 0; rt < 2; ++rt)
      #pragma unroll
      for (int reg = 0; reg < 4; ++reg) {
        const int row = rw * 32 + rt * 16 + q * 4 + reg;
        u32x2 kv = {k1[rt * 4 + reg], k2[rt * 4 + reg]};
        *(u32x2*)(EsU + row * 256 + (cw * 16 + l15) * 8) = kv;
      }

    // ---- merge top-2 across the 16 l15-lanes sharing each row (disjoint codes) ----
    #pragma unroll
    for (int s = 0; s < 8; ++s) {
      #pragma unroll
      for (int off = 1; off < 16; off <<= 1) {
        unsigned o1 = __shfl_xor(k1[s], off);
        unsigned o2 = __shfl_xor(k2[s], off);
        unsigned mn = umn(k1[s], o1);
        k1[s] = umx(k1[s], o1);
        k2[s] = umx(mn, umx(k2[s], o2));
      }
    }
    if (l15 == 0) {
      #pragma unroll
      for (int rt = 0; rt < 2; ++rt)
        #pragma unroll
        for (int reg = 0; reg < 4; ++reg) {
          const int row = rw * 32 + rt * 16 + q * 4 + reg;
          redk[row][cw][0] = k1[rt * 4 + reg];
          redk[row][cw][1] = k2[rt * 4 + reg];
        }
    }
    __syncthreads();              // cand table + redk visible

    // ---- final per-row merge (2 cw halves), flag into block-local list ----
    if (tid < RROWS) {
      unsigned a1 = redk[tid][0][0], a2 = redk[tid][0][1];
      unsigned b1 = redk[tid][1][0], b2 = redk[tid][1][1];
      unsigned f1 = umx(a1, b1);
      unsigned f2 = umx(umn(a1, b1), umx(a2, b2));
      bcode[tid] = 1023 - (int)(f1 & 1023u);
      float d1 = __uint_as_float(f1 & 0xFFFFFC00u);
      float d2 = __uint_as_float(f2 & 0xFFFFFC00u);
      if (d1 - d2 <= THRQ) {
        int p = atomicAdd(&fcnt, 1);
        frows[p] = tid;
      }
    }
    __syncthreads();              // flags + bcode visible
    const int nf = fcnt;

    // ---- exact candidate fixup: one wave per flagged row, lane per candidate ----
    // 64 candidates = 32 streams x top-2. Validated arithmetic: sequential-k
    // fmaf chain, 2.0f*acc - enorm (unbiased exact scale), lowest-index ties.
    for (int f = wv; f < nf; f += 4) {
      const int r = frows[f];
      const unsigned key = *(const unsigned*)(EsU + r * 256 + (lane >> 1) * 8 + (lane & 1) * 4);
      const int c = 1023 - (int)(key & 1023u);
      const float* rv = &resid[r][0];                // LDS, wave-uniform row
      const float* ev = embS + (size_t)c * DDIM;     // per-lane code row (L2-hot)
      float a = 0.f;
      #pragma unroll 4
      for (int k4 = 0; k4 < 32; ++k4) {
        float4 rr = *(const float4*)(rv + k4 * 4);
        float4 e4 = *(const float4*)(ev + k4 * 4);
        a = fmaf(rr.x, e4.x, a); a = fmaf(rr.y, e4.y, a);
        a = fmaf(rr.z, e4.z, a); a = fmaf(rr.w, e4.w, a);
      }
      float bv = 2.0f * a - enS[c];
      int bi = c;
      #pragma unroll
      for (int off = 32; off > 0; off >>= 1) {
        float o = __shfl_down(bv, off);
        int oi = __shfl_down(bi, off);
        if (o > bv || (o == bv && oi < bi)) { bv = o; bi = oi; }
      }
      if (lane == 0) bcode[r] = bi;
    }
    __syncthreads();              // corrected bcode visible
    if (tid == 0) fcnt = 0;       // next write behind >=1 barrier, reads done

    // ---- codes out + exact f32 residual update in LDS (final codes) ----
    if (tid < RROWS) codes[(size_t)st * M_TOTAL + row_base + tid] = bcode[tid];
    if (st < NQ - 1) {
      #pragma unroll
      for (int it = 0; it < 8; ++it) {
        int idx = it * 256 + tid;
        int r = idx >> 5, f4 = idx & 31;
        float4 e = *(const float4*)(embS + (size_t)bcode[r] * DDIM + f4 * 4);
        float4 a = *(const float4*)(&resid[r][f4 * 4]);
        a.x -= e.x; a.y -= e.y; a.z -= e.z; a.w -= e.w;
        *(float4*)(&resid[r][f4 * 4]) = a;   // owner-exclusive (r,f4)
      }
    }
    __syncthreads();              // resid update + fcnt reset ordered vs next stage
  }
}

// ================= fallback: round-2 verified exact-fp32 kernel =================
#define F_NCHUNK  256
#define F_KC      16
#define F_AS_STRIDE 68
#define F_ES_STRIDE 260

__global__ __launch_bounds__(256, 3) void rvq_stage_kernel(
    const float* __restrict__ rin, float* __restrict__ rout,
    const float* __restrict__ embed, const float* __restrict__ enorm,
    int* __restrict__ codes)
{
  __shared__ float smem[DDIM * F_AS_STRIDE + F_KC * F_ES_STRIDE + F_NCHUNK];
  float* As  = smem;
  float* Es  = smem + DDIM * F_AS_STRIDE;
  float* Ens = Es + F_KC * F_ES_STRIDE;
  float* red_v = Es;
  int*   red_i = (int*)(Es + 64 * 33);
  int*   bcode = (int*)(Es + 2 * 64 * 33);

  const int tid = threadIdx.x;
  const int tx = tid & 31;
  const int ty = tid >> 5;
  const int row_base = blockIdx.x * 64;

  #pragma unroll
  for (int it = 0; it < 8; ++it) {
    int idx = it * 256 + tid;
    int r = idx >> 5, f4 = idx & 31;
    float4 v = *(const float4*)(rin + (size_t)(row_base + r) * DDIM + f4 * 4);
    As[(4 * f4 + 0) * F_AS_STRIDE + r] = v.x;
    As[(4 * f4 + 1) * F_AS_STRIDE + r] = v.y;
    As[(4 * f4 + 2) * F_AS_STRIDE + r] = v.z;
    As[(4 * f4 + 3) * F_AS_STRIDE + r] = v.w;
  }

  float best[8]; int bidx[8];
  #pragma unroll
  for (int i = 0; i < 8; ++i) { best[i] = -3.0e38f; bidx[i] = 0x7fffffff; }

  for (int nc = 0; nc < KCODES / F_NCHUNK; ++nc) {
    float acc[8][8];
    #pragma unroll
    for (int i = 0; i < 8; ++i)
      #pragma unroll
      for (int j = 0; j < 8; ++j) acc[i][j] = 0.0f;

    for (int kc = 0; kc < DDIM / F_KC; ++kc) {
      __syncthreads();
      #pragma unroll
      for (int it = 0; it < 4; ++it) {
        int idx = it * 256 + tid;
        int c = idx >> 2, f4 = idx & 3;
        float4 v = *(const float4*)(embed + (size_t)(nc * F_NCHUNK + c) * DDIM + kc * F_KC + f4 * 4);
        Es[(4 * f4 + 0) * F_ES_STRIDE + c] = v.x;
        Es[(4 * f4 + 1) * F_ES_STRIDE + c] = v.y;
        Es[(4 * f4 + 2) * F_ES_STRIDE + c] = v.z;
        Es[(4 * f4 + 3) * F_ES_STRIDE + c] = v.w;
      }
      if (kc == 0) Ens[tid] = enorm[nc * F_NCHUNK + tid];
      __syncthreads();

      const float* pa = As + kc * F_KC * F_AS_STRIDE + ty * 8;
      const float* pe = Es + 4 * tx;
      #pragma unroll 4
      for (int k = 0; k < F_KC; ++k) {
        float4 a0 = *(const float4*)(pa + k * F_AS_STRIDE);
        float4 a1 = *(const float4*)(pa + k * F_AS_STRIDE + 4);
        float4 e0 = *(const float4*)(pe + k * F_ES_STRIDE);
        float4 e1 = *(const float4*)(pe + k * F_ES_STRIDE + 128);
        float aa[8] = {a0.x, a0.y, a0.z, a0.w, a1.x, a1.y, a1.z, a1.w};
        float ee[8] = {e0.x, e0.y, e0.z, e0.w, e1.x, e1.y, e1.z, e1.w};
        #pragma unroll
        for (int i = 0; i < 8; ++i)
          #pragma unroll
          for (int j = 0; j < 8; ++j)
            acc[i][j] = fmaf(aa[i], ee[j], acc[i][j]);
      }
    }

    #pragma unroll
    for (int j = 0; j < 8; ++j) {
      int c_local = (j < 4) ? (4 * tx + j) : (128 + 4 * tx + (j - 4));
      float en = Ens[c_local];
      int cg = nc * F_NCHUNK + c_local;
      #pragma unroll
      for (int i = 0; i < 8; ++i) {
        float dist = 2.0f * acc[i][j] - en;
        if (dist > best[i] || (dist == best[i] && cg < bidx[i])) { best[i] = dist; bidx[i] = cg; }
      }
    }
  }

  __syncthreads();
  #pragma unroll
  for (int i = 0; i < 8; ++i) {
    red_v[(ty * 8 + i) * 33 + tx] = best[i];
    red_i[(ty * 8 + i) * 33 + tx] = bidx[i];
  }
  __syncthreads();
  if (tid < 64) {
    float bv = red_v[tid * 33]; int bi = red_i[tid * 33];
    #pragma unroll
    for (int t = 1; t < 32; ++t) {
      float v = red_v[tid * 33 + t]; int ix = red_i[tid * 33 + t];
      if (v > bv || (v == bv && ix < bi)) { bv = v; bi = ix; }
    }
    codes[row_base + tid] = bi;
    bcode[tid] = bi;
  }
  __syncthreads();
  #pragma unroll
  for (int it = 0; it < 32; ++it) {
    int idx = it * 256 + tid;
    int r = idx >> 7, d = idx & 127;
    float e = embed[(size_t)bcode[r] * DDIM + d];
    rout[(size_t)(row_base + r) * DDIM + d] = As[d * F_AS_STRIDE + r] - e;
  }
}

extern "C" void kernel_launch(void* const* d_in, const int* in_sizes, int n_in,
                              void* d_out, int out_size, void* d_ws, size_t ws_size,
                              hipStream_t stream) {
  (void)in_sizes; (void)n_in; (void)out_size;
  const float* x = (const float*)d_in[0];
  const float* embed = (const float*)d_in[1];
  int* codes = (int*)d_out;

  const size_t E16_BYTES = (size_t)NQ * KCODES * DDIM * 2;        // 2 MB f16 codebook
  const size_t EN_BYTES  = (size_t)NQ * KCODES * 4;               // 32 KB
  const size_t need = E16_BYTES + EN_BYTES + 256;

  if (ws_size >= need) {
    char* w = (char*)d_ws;
    _Float16* Ef16 = (_Float16*)w;     w += E16_BYTES;
    float* enorm   = (float*)w;

    enorm_kernel<<<dim3(NQ * KCODES / 4), dim3(256), 0, stream>>>(embed, enorm);
    esplit16_kernel<<<dim3(NQ * KCODES * DDIM / 8 / 256), dim3(256), 0, stream>>>(embed, Ef16);
    rvq_fused<<<dim3(M_TOTAL / RROWS), dim3(256), 0, stream>>>(
        x, embed, Ef16, enorm, codes);
  } else {
    // fallback: verified round-2 exact-fp32 path
    const size_t resid_elems = (size_t)M_TOTAL * DDIM;
    const bool ws_ok = ws_size >= (resid_elems + (size_t)NQ * KCODES) * sizeof(float);
    float* resid = ws_ok ? (float*)d_ws : (float*)d_in[0];
    float* enorm = ws_ok ? ((float*)d_ws + resid_elems) : (float*)d_ws;

    enorm_kernel<<<dim3(NQ * KCODES / 4), dim3(256), 0, stream>>>(embed, enorm);
    for (int q = 0; q < NQ; ++q) {
      const float* rin = (q == 0) ? x : resid;
      rvq_stage_kernel<<<dim3(M_TOTAL / 64), dim3(256), 0, stream>>>(
          rin, resid, embed + (size_t)q * KCODES * DDIM,
          enorm + (size_t)q * KCODES, codes + (size_t)q * M_TOTAL);
    }
  }
}

// Round 10
// 360.787 us; speedup vs baseline: 12.8258x; 1.0039x over previous
//
#include <hip/hip_runtime.h>

#define M_TOTAL 65536   // B*T rows
#define DDIM    128     // latent dim (GEMM K)
#define KCODES  1024    // codebook size (GEMM N)
#define NQ      8       // RVQ stages
#define RROWS   64      // rows per block -> 1024 blocks, 2/CU co-resident (2 passes)
#define NC      64      // codes per Es chunk
#define NCHUNKS (KCODES / NC)          // 16
#define CHUNK_B (NC * DDIM * 2)        // 16384 B per f16 chunk
#define BIAS    320.0f  // folded into acc init: keys strictly positive (12+ sigma margin)
#define THRQ    0.106f  // screen-unit flag threshold = validated 0.075 + 0.031 quant guard

typedef _Float16 half8 __attribute__((ext_vector_type(8)));
typedef float    f32x4 __attribute__((ext_vector_type(4)));
typedef unsigned u32x2 __attribute__((ext_vector_type(2)));

__device__ __forceinline__ unsigned umx(unsigned a, unsigned b) { return a > b ? a : b; }
__device__ __forceinline__ unsigned umn(unsigned a, unsigned b) { return a < b ? a : b; }

// direct global->LDS copy, 16 B per lane; LDS dest is wave-uniform base + lane*16
__device__ __forceinline__ void gld_lds16(const void* g, void* l) {
  __builtin_amdgcn_global_load_lds(
      (const __attribute__((address_space(1))) unsigned int*)g,
      (__attribute__((address_space(3))) unsigned int*)l, 16, 0, 0);
}

// ---------------- ||e||^2 (verified round-1 semantics) ----------------
__global__ __launch_bounds__(256) void enorm_kernel(const float* __restrict__ embed,
                                                    float* __restrict__ enorm) {
  int c = blockIdx.x * 4 + (threadIdx.x >> 6);
  int lane = threadIdx.x & 63;
  const float* e = embed + (size_t)c * DDIM;
  float v0 = e[lane];
  float v1 = e[lane + 64];
  float s = fmaf(v0, v0, v1 * v1);
  #pragma unroll
  for (int off = 32; off > 0; off >>= 1) s += __shfl_down(s, off);
  if (lane == 0) enorm[c] = s;
}

// ---------------- embed -> f16 plane, PRE-SWIZZLED for linear global_load_lds ----
__global__ __launch_bounds__(256) void esplit16_kernel(const float* __restrict__ embed,
                                                       _Float16* __restrict__ Ef16) {
  unsigned u = blockIdx.x * 256 + threadIdx.x;          // half8 index: ((s*1024+c)*16+j)
  size_t src = (size_t)u * 8;
  float4 v0 = *(const float4*)(embed + src);
  float4 v1 = *(const float4*)(embed + src + 4);
  half8 h;
  h[0] = (_Float16)v0.x; h[1] = (_Float16)v0.y; h[2] = (_Float16)v0.z; h[3] = (_Float16)v0.w;
  h[4] = (_Float16)v1.x; h[5] = (_Float16)v1.y; h[6] = (_Float16)v1.z; h[7] = (_Float16)v1.w;
  unsigned row = u >> 4;                                // s*1024 + c
  unsigned j   = u & 15;
  size_t dst = (size_t)row * 128 + 8 * (j ^ (row & 7)); // (row&7) == (c&7)
  *(half8*)(Ef16 + dst) = h;
}

// ---------------- fused 8-stage RVQ: LDS residual + dbuf Es + packed-key top-2 ----
// r9 machinery (LDS resid [64][132], 2x2 wave grid, packed sortable keys,
// candidate fixup -- all validated absmax 0) with the chunk loop restored to
// the r0/r7-proven DOUBLE-BUFFERED single-barrier form: loads for chunk cc+1
// issue FIRST in the body of cc, so the vmcnt drain at the lone barrier comes
// ~350 cy after issue (vs ~200 cy in r9's 2-barrier single-buffer loop), and
// barriers halve (16/stage). Cost: LDS 68.1 KB -> 2 blocks/CU. This is the
// pipeline-depth-vs-occupancy A/B; r9's per-chunk drain stall exceeds the
// co-residency it buys, by cycle accounting.
__global__ __launch_bounds__(256, 2) void rvq_fused(
    const float* __restrict__ x,          // [M_TOTAL][DDIM] f32
    const float* __restrict__ embed,      // [NQ][KCODES][DDIM] f32
    const _Float16* __restrict__ Ef16,    // [NQ][KCODES][DDIM] f16, pre-swizzled
    const float* __restrict__ enorm,      // [NQ][KCODES]
    int* __restrict__ codes)              // [NQ][M_TOTAL]
{
  __shared__ __attribute__((aligned(16))) float resid[RROWS][132];   // 33792 B
  __shared__ __attribute__((aligned(16))) char EsU[2 * CHUNK_B];     // 32768 B (dbuf / cand)
  __shared__ unsigned redk[RROWS][2][2];                             // 1024 B
  __shared__ int bcode[RROWS];
  __shared__ int frows[RROWS];
  __shared__ int fcnt;

  const int tid = threadIdx.x;
  const int wv = tid >> 6;
  const int lane = tid & 63;
  const int l15 = lane & 15;
  const int q = lane >> 4;
  const int rw = wv & 1;          // row-half of the 2x2 wave grid
  const int cw = wv >> 1;         // code-half
  const int row_base = blockIdx.x * RROWS;
  const int rx = cw * 32 + l15;   // B-frag row within chunk (ct=0); ct=1 adds 16
  const int xr = rx & 7;          // Es bank swizzle key (rx and rx+16 share it)

  // ---- x -> LDS residual (once, coalesced) ----
  #pragma unroll
  for (int it = 0; it < 8; ++it) {
    int idx = it * 256 + tid;
    int r = idx >> 5, f4 = idx & 31;
    *(float4*)(&resid[r][f4 * 4]) = *(const float4*)(x + (size_t)(row_base + r) * DDIM + f4 * 4);
  }
  if (tid == 0) fcnt = 0;
  __syncthreads();

  for (int st = 0; st < NQ; ++st) {
    const _Float16* EfS = Ef16 + (size_t)st * KCODES * DDIM;
    const float* enS = enorm + (size_t)st * KCODES;
    const float* embS = embed + (size_t)st * KCODES * DDIM;

    // ---- f16 A-frags from LDS residual: af[rt][kc], rows rw*32+rt*16+l15 ----
    half8 af[2][4];
    #pragma unroll
    for (int rt = 0; rt < 2; ++rt) {
      const float* pa = &resid[rw * 32 + rt * 16 + l15][0];
      #pragma unroll
      for (int kc = 0; kc < 4; ++kc) {
        float4 x0 = *(const float4*)(pa + kc * 32 + q * 8);
        float4 x1 = *(const float4*)(pa + kc * 32 + q * 8 + 4);
        half8 h;
        h[0] = (_Float16)x0.x; h[1] = (_Float16)x0.y; h[2] = (_Float16)x0.z; h[3] = (_Float16)x0.w;
        h[4] = (_Float16)x1.x; h[5] = (_Float16)x1.y; h[6] = (_Float16)x1.z; h[7] = (_Float16)x1.w;
        af[rt][kc] = h;
      }
    }

    // ---- prologue: stage chunk 0 into buf 0 (linear gld_lds == swizzled layout) ----
    {
      const char* g = (const char*)EfS;
      #pragma unroll
      for (int it = 0; it < 4; ++it) {
        const int off = it * 4096 + wv * 1024;
        gld_lds16(g + off + lane * 16, EsU + off);
      }
    }
    float enr0 = enS[cw * 32 + l15];
    float enr1 = enS[cw * 32 + 16 + l15];
    __syncthreads();              // chunk 0 staged (vmcnt drained); A-frag reads done

    // 8 key-pair streams/thread: stream (rt,reg) = row rw*32+rt*16+q*4+reg,
    // codes {cc*64 + cw*32 + ct*16 + l15}. 32 codes/stream.
    unsigned k1[8], k2[8];
    #pragma unroll
    for (int s = 0; s < 8; ++s) { k1[s] = 0u; k2[s] = 0u; }

    for (int cc = 0; cc < NCHUNKS; ++cc) {
      const int cur = cc & 1;
      // issue next chunk FIRST: full MFMA+epilogue window covers the L2 latency
      if (cc + 1 < NCHUNKS) {
        const char* g = (const char*)EfS + (size_t)(cc + 1) * CHUNK_B;
        char* l = EsU + (cur ^ 1) * CHUNK_B;
        #pragma unroll
        for (int it = 0; it < 4; ++it) {
          const int off = it * 4096 + wv * 1024;
          gld_lds16(g + off + lane * 16, l + off);
        }
      }
      float nh0 = BIAS - 0.5f * enr0;  // biased: d = BIAS + dot - ||e||^2/2 > 0
      float nh1 = BIAS - 0.5f * enr1;
      if (cc + 1 < NCHUNKS) {          // pipeline next chunk's enorm
        enr0 = enS[(cc + 1) * NC + cw * 32 + l15];
        enr1 = enS[(cc + 1) * NC + cw * 32 + 16 + l15];
      }
      f32x4 acc[2][2];
      #pragma unroll
      for (int rt = 0; rt < 2; ++rt) {
        acc[rt][0] = (f32x4){nh0, nh0, nh0, nh0};
        acc[rt][1] = (f32x4){nh1, nh1, nh1, nh1};
      }

      const char* eb = EsU + cur * CHUNK_B;
      #pragma unroll
      for (int kc = 0; kc < 4; ++kc) {
        const int jswz = 16 * ((kc * 4 + q) ^ xr);
        half8 bf0 = *(const half8*)(eb + rx * 256 + jswz);
        half8 bf1 = *(const half8*)(eb + (rx + 16) * 256 + jswz);
        #pragma unroll
        for (int rt = 0; rt < 2; ++rt) {
          acc[rt][0] = __builtin_amdgcn_mfma_f32_16x16x32_f16(af[rt][kc], bf0, acc[rt][0], 0, 0, 0);
          acc[rt][1] = __builtin_amdgcn_mfma_f32_16x16x32_f16(af[rt][kc], bf1, acc[rt][1], 0, 0, 0);
        }
      }

      // ---- packed-key top-2 epilogue (distinct keys -> exact low-index ties) ----
      const unsigned revb = 1023u - (unsigned)(cc * NC + cw * 32 + l15);  // ct=0
      #pragma unroll
      for (int rt = 0; rt < 2; ++rt)
        #pragma unroll
        for (int reg = 0; reg < 4; ++reg) {
          const int s = rt * 4 + reg;
          unsigned kk0 = (__float_as_uint(acc[rt][0][reg]) & 0xFFFFFC00u) | revb;
          k2[s] = umx(umn(kk0, k1[s]), k2[s]);
          k1[s] = umx(k1[s], kk0);
          unsigned kk1 = (__float_as_uint(acc[rt][1][reg]) & 0xFFFFFC00u) | (revb - 16u);
          k2[s] = umx(umn(kk1, k1[s]), k2[s]);
          k1[s] = umx(k1[s], kk1);
        }
      __syncthreads();            // ONE barrier/chunk: next buf staged, cur consumed
    }
    // EsU dead -> candidate table [row][cw*16+l15] = {k1,k2} (8 B/stream, 16 KB)

    // ---- candidate dump (pre-merge per-stream top-2) ----
    #pragma unroll
    for (int rt = 0; rt < 2; ++rt)
      #pragma unroll
      for (int reg = 0; reg < 4; ++reg) {
        const int row = rw * 32 + rt * 16 + q * 4 + reg;
        u32x2 kv = {k1[rt * 4 + reg], k2[rt * 4 + reg]};
        *(u32x2*)(EsU + row * 256 + (cw * 16 + l15) * 8) = kv;
      }

    // ---- merge top-2 across the 16 l15-lanes sharing each row (disjoint codes) ----
    #pragma unroll
    for (int s = 0; s < 8; ++s) {
      #pragma unroll
      for (int off = 1; off < 16; off <<= 1) {
        unsigned o1 = __shfl_xor(k1[s], off);
        unsigned o2 = __shfl_xor(k2[s], off);
        unsigned mn = umn(k1[s], o1);
        k1[s] = umx(k1[s], o1);
        k2[s] = umx(mn, umx(k2[s], o2));
      }
    }
    if (l15 == 0) {
      #pragma unroll
      for (int rt = 0; rt < 2; ++rt)
        #pragma unroll
        for (int reg = 0; reg < 4; ++reg) {
          const int row = rw * 32 + rt * 16 + q * 4 + reg;
          redk[row][cw][0] = k1[rt * 4 + reg];
          redk[row][cw][1] = k2[rt * 4 + reg];
        }
    }
    __syncthreads();              // cand table + redk visible

    // ---- final per-row merge (2 cw halves), flag into block-local list ----
    if (tid < RROWS) {
      unsigned a1 = redk[tid][0][0], a2 = redk[tid][0][1];
      unsigned b1 = redk[tid][1][0], b2 = redk[tid][1][1];
      unsigned f1 = umx(a1, b1);
      unsigned f2 = umx(umn(a1, b1), umx(a2, b2));
      bcode[tid] = 1023 - (int)(f1 & 1023u);
      float d1 = __uint_as_float(f1 & 0xFFFFFC00u);
      float d2 = __uint_as_float(f2 & 0xFFFFFC00u);
      if (d1 - d2 <= THRQ) {
        int p = atomicAdd(&fcnt, 1);
        frows[p] = tid;
      }
    }
    __syncthreads();              // flags + bcode visible
    const int nf = fcnt;

    // ---- exact candidate fixup: one wave per flagged row, lane per candidate ----
    // 64 candidates = 32 streams x top-2. Validated arithmetic: sequential-k
    // fmaf chain, 2.0f*acc - enorm (unbiased exact scale), lowest-index ties.
    for (int f = wv; f < nf; f += 4) {
      const int r = frows[f];
      const unsigned key = *(const unsigned*)(EsU + r * 256 + (lane >> 1) * 8 + (lane & 1) * 4);
      const int c = 1023 - (int)(key & 1023u);
      const float* rv = &resid[r][0];                // LDS, wave-uniform row
      const float* ev = embS + (size_t)c * DDIM;     // per-lane code row (L2-hot)
      float a = 0.f;
      #pragma unroll 4
      for (int k4 = 0; k4 < 32; ++k4) {
        float4 rr = *(const float4*)(rv + k4 * 4);
        float4 e4 = *(const float4*)(ev + k4 * 4);
        a = fmaf(rr.x, e4.x, a); a = fmaf(rr.y, e4.y, a);
        a = fmaf(rr.z, e4.z, a); a = fmaf(rr.w, e4.w, a);
      }
      float bv = 2.0f * a - enS[c];
      int bi = c;
      #pragma unroll
      for (int off = 32; off > 0; off >>= 1) {
        float o = __shfl_down(bv, off);
        int oi = __shfl_down(bi, off);
        if (o > bv || (o == bv && oi < bi)) { bv = o; bi = oi; }
      }
      if (lane == 0) bcode[r] = bi;
    }
    __syncthreads();              // corrected bcode visible
    if (tid == 0) fcnt = 0;       // next write behind >=1 barrier, reads done

    // ---- codes out + exact f32 residual update in LDS (final codes) ----
    if (tid < RROWS) codes[(size_t)st * M_TOTAL + row_base + tid] = bcode[tid];
    if (st < NQ - 1) {
      #pragma unroll
      for (int it = 0; it < 8; ++it) {
        int idx = it * 256 + tid;
        int r = idx >> 5, f4 = idx & 31;
        float4 e = *(const float4*)(embS + (size_t)bcode[r] * DDIM + f4 * 4);
        float4 a = *(const float4*)(&resid[r][f4 * 4]);
        a.x -= e.x; a.y -= e.y; a.z -= e.z; a.w -= e.w;
        *(float4*)(&resid[r][f4 * 4]) = a;   // owner-exclusive (r,f4)
      }
    }
    __syncthreads();              // resid update + fcnt reset ordered vs next stage
  }
}

// ================= fallback: round-2 verified exact-fp32 kernel =================
#define F_NCHUNK  256
#define F_KC      16
#define F_AS_STRIDE 68
#define F_ES_STRIDE 260

__global__ __launch_bounds__(256, 3) void rvq_stage_kernel(
    const float* __restrict__ rin, float* __restrict__ rout,
    const float* __restrict__ embed, const float* __restrict__ enorm,
    int* __restrict__ codes)
{
  __shared__ float smem[DDIM * F_AS_STRIDE + F_KC * F_ES_STRIDE + F_NCHUNK];
  float* As  = smem;
  float* Es  = smem + DDIM * F_AS_STRIDE;
  float* Ens = Es + F_KC * F_ES_STRIDE;
  float* red_v = Es;
  int*   red_i = (int*)(Es + 64 * 33);
  int*   bcode = (int*)(Es + 2 * 64 * 33);

  const int tid = threadIdx.x;
  const int tx = tid & 31;
  const int ty = tid >> 5;
  const int row_base = blockIdx.x * 64;

  #pragma unroll
  for (int it = 0; it < 8; ++it) {
    int idx = it * 256 + tid;
    int r = idx >> 5, f4 = idx & 31;
    float4 v = *(const float4*)(rin + (size_t)(row_base + r) * DDIM + f4 * 4);
    As[(4 * f4 + 0) * F_AS_STRIDE + r] = v.x;
    As[(4 * f4 + 1) * F_AS_STRIDE + r] = v.y;
    As[(4 * f4 + 2) * F_AS_STRIDE + r] = v.z;
    As[(4 * f4 + 3) * F_AS_STRIDE + r] = v.w;
  }

  float best[8]; int bidx[8];
  #pragma unroll
  for (int i = 0; i < 8; ++i) { best[i] = -3.0e38f; bidx[i] = 0x7fffffff; }

  for (int nc = 0; nc < KCODES / F_NCHUNK; ++nc) {
    float acc[8][8];
    #pragma unroll
    for (int i = 0; i < 8; ++i)
      #pragma unroll
      for (int j = 0; j < 8; ++j) acc[i][j] = 0.0f;

    for (int kc = 0; kc < DDIM / F_KC; ++kc) {
      __syncthreads();
      #pragma unroll
      for (int it = 0; it < 4; ++it) {
        int idx = it * 256 + tid;
        int c = idx >> 2, f4 = idx & 3;
        float4 v = *(const float4*)(embed + (size_t)(nc * F_NCHUNK + c) * DDIM + kc * F_KC + f4 * 4);
        Es[(4 * f4 + 0) * F_ES_STRIDE + c] = v.x;
        Es[(4 * f4 + 1) * F_ES_STRIDE + c] = v.y;
        Es[(4 * f4 + 2) * F_ES_STRIDE + c] = v.z;
        Es[(4 * f4 + 3) * F_ES_STRIDE + c] = v.w;
      }
      if (kc == 0) Ens[tid] = enorm[nc * F_NCHUNK + tid];
      __syncthreads();

      const float* pa = As + kc * F_KC * F_AS_STRIDE + ty * 8;
      const float* pe = Es + 4 * tx;
      #pragma unroll 4
      for (int k = 0; k < F_KC; ++k) {
        float4 a0 = *(const float4*)(pa + k * F_AS_STRIDE);
        float4 a1 = *(const float4*)(pa + k * F_AS_STRIDE + 4);
        float4 e0 = *(const float4*)(pe + k * F_ES_STRIDE);
        float4 e1 = *(const float4*)(pe + k * F_ES_STRIDE + 128);
        float aa[8] = {a0.x, a0.y, a0.z, a0.w, a1.x, a1.y, a1.z, a1.w};
        float ee[8] = {e0.x, e0.y, e0.z, e0.w, e1.x, e1.y, e1.z, e1.w};
        #pragma unroll
        for (int i = 0; i < 8; ++i)
          #pragma unroll
          for (int j = 0; j < 8; ++j)
            acc[i][j] = fmaf(aa[i], ee[j], acc[i][j]);
      }
    }

    #pragma unroll
    for (int j = 0; j < 8; ++j) {
      int c_local = (j < 4) ? (4 * tx + j) : (128 + 4 * tx + (j - 4));
      float en = Ens[c_local];
      int cg = nc * F_NCHUNK + c_local;
      #pragma unroll
      for (int i = 0; i < 8; ++i) {
        float dist = 2.0f * acc[i][j] - en;
        if (dist > best[i] || (dist == best[i] && cg < bidx[i])) { best[i] = dist; bidx[i] = cg; }
      }
    }
  }

  __syncthreads();
  #pragma unroll
  for (int i = 0; i < 8; ++i) {
    red_v[(ty * 8 + i) * 33 + tx] = best[i];
    red_i[(ty * 8 + i) * 33 + tx] = bidx[i];
  }
  __syncthreads();
  if (tid < 64) {
    float bv = red_v[tid * 33]; int bi = red_i[tid * 33];
    #pragma unroll
    for (int t = 1; t < 32; ++t) {
      float v = red_v[tid * 33 + t]; int ix = red_i[tid * 33 + t];
      if (v > bv || (v == bv && ix < bi)) { bv = v; bi = ix; }
    }
    codes[row_base + tid] = bi;
    bcode[tid] = bi;
  }
  __syncthreads();
  #pragma unroll
  for (int it = 0; it < 32; ++it) {
    int idx = it * 256 + tid;
    int r = idx >> 7, d = idx & 127;
    float e = embed[(size_t)bcode[r] * DDIM + d];
    rout[(size_t)(row_base + r) * DDIM + d] = As[d * F_AS_STRIDE + r] - e;
  }
}

extern "C" void kernel_launch(void* const* d_in, const int* in_sizes, int n_in,
                              void* d_out, int out_size, void* d_ws, size_t ws_size,
                              hipStream_t stream) {
  (void)in_sizes; (void)n_in; (void)out_size;
  const float* x = (const float*)d_in[0];
  const float* embed = (const float*)d_in[1];
  int* codes = (int*)d_out;

  const size_t E16_BYTES = (size_t)NQ * KCODES * DDIM * 2;        // 2 MB f16 codebook
  const size_t EN_BYTES  = (size_t)NQ * KCODES * 4;               // 32 KB
  const size_t need = E16_BYTES + EN_BYTES + 256;

  if (ws_size >= need) {
    char* w = (char*)d_ws;
    _Float16* Ef16 = (_Float16*)w;     w += E16_BYTES;
    float* enorm   = (float*)w;

    enorm_kernel<<<dim3(NQ * KCODES / 4), dim3(256), 0, stream>>>(embed, enorm);
    esplit16_kernel<<<dim3(NQ * KCODES * DDIM / 8 / 256), dim3(256), 0, stream>>>(embed, Ef16);
    rvq_fused<<<dim3(M_TOTAL / RROWS), dim3(256), 0, stream>>>(
        x, embed, Ef16, enorm, codes);
  } else {
    // fallback: verified round-2 exact-fp32 path
    const size_t resid_elems = (size_t)M_TOTAL * DDIM;
    const bool ws_ok = ws_size >= (resid_elems + (size_t)NQ * KCODES) * sizeof(float);
    float* resid = ws_ok ? (float*)d_ws : (float*)d_in[0];
    float* enorm = ws_ok ? ((float*)d_ws + resid_elems) : (float*)d_ws;

    enorm_kernel<<<dim3(NQ * KCODES / 4), dim3(256), 0, stream>>>(embed, enorm);
    for (int q = 0; q < NQ; ++q) {
      const float* rin = (q == 0) ? x : resid;
      rvq_stage_kernel<<<dim3(M_TOTAL / 64), dim3(256), 0, stream>>>(
          rin, resid, embed + (size_t)q * KCODES * DDIM,
          enorm + (size_t)q * KCODES, codes + (size_t)q * M_TOTAL);
    }
  }
}